// Round 4
// baseline (442.677 us; speedup 1.0000x reference)
//
#include <hip/hip_runtime.h>

typedef unsigned short ushort_t;
typedef unsigned int uint_t;
typedef __bf16 bf16x8 __attribute__((ext_vector_type(8)));
typedef float f32x4 __attribute__((ext_vector_type(4)));

#define BM 128
#define BN 128

static constexpr float LRC  = 0.3f;
static constexpr float AC   = (float)(0.3 * 1e-4);          // LR*DSBETA
static constexpr float OMAC = (float)(1.0 - 0.3 * 1e-4);    // 1 - LR*DSBETA
static constexpr float EPSC = 0.01f;                        // EPS_DS
static constexpr float ATC  = 0.9f;                         // AT

__device__ __forceinline__ void gll16(const void* g, void* l) {
    __builtin_amdgcn_global_load_lds((__attribute__((address_space(1))) void*)g,
                                     (__attribute__((address_space(3))) void*)l,
                                     16, 0, 0);
}

__device__ __forceinline__ ushort_t f2bf_rne(float f) {
    uint_t u = __float_as_uint(f);
    uint_t r = u + 0x7fffu + ((u >> 16) & 1u);
    return (ushort_t)(r >> 16);
}

// -------- kernel A: X -> (hi,mid,lo) bf16 split + ||x||^2 (fused) ------------
__global__ __launch_bounds__(128) void k_prep_x(
    const float* __restrict__ X, ushort_t* __restrict__ Xh,
    ushort_t* __restrict__ Xm, ushort_t* __restrict__ Xl,
    float* __restrict__ xsq, int D)
{
    int b = blockIdx.x, t = threadIdx.x;
    const float4* xr = (const float4*)(X + (size_t)b * D);
    float q = 0.f;
    for (int i = t; i < (D >> 2); i += 128) {
        float4 v = xr[i];
        float x[4] = {v.x, v.y, v.z, v.w};
        ushort_t h[4], m[4], l[4];
#pragma unroll
        for (int j = 0; j < 4; j++) {
            q += x[j] * x[j];
            h[j] = f2bf_rne(x[j]);
            float hf = __uint_as_float(((uint_t)h[j]) << 16);
            float r1 = x[j] - hf;
            m[j] = f2bf_rne(r1);
            float mf = __uint_as_float(((uint_t)m[j]) << 16);
            l[j] = f2bf_rne(r1 - mf);
        }
        size_t o = (size_t)b * (D >> 2) + i;
        ((ushort4*)Xh)[o] = make_ushort4(h[0], h[1], h[2], h[3]);
        ((ushort4*)Xm)[o] = make_ushort4(m[0], m[1], m[2], m[3]);
        ((ushort4*)Xl)[o] = make_ushort4(l[0], l[1], l[2], l[3]);
    }
    __shared__ float s1[128];
    s1[t] = q; __syncthreads();
    for (int off = 64; off > 0; off >>= 1) {
        if (t < off) s1[t] += s1[t + off];
        __syncthreads();
    }
    if (t == 0) xsq[b] = s1[0];
}

// ---- kernel B: W -> (hi,mid,lo) split + rel_sum + ||w||^2 (fused) -----------
__global__ __launch_bounds__(128) void k_prep_w(
    const float* __restrict__ W, const float* __restrict__ REL,
    ushort_t* __restrict__ Wh, ushort_t* __restrict__ Wm,
    ushort_t* __restrict__ Wl,
    float* __restrict__ rel_sum, float* __restrict__ wsq, int D)
{
    int k = blockIdx.x, t = threadIdx.x;
    const float4* wr = (const float4*)(W + (size_t)k * D);
    const float4* rr = (const float4*)(REL + (size_t)k * D);
    float q = 0.f, r = 0.f;
    for (int i = t; i < (D >> 2); i += 128) {
        float4 v = wr[i];
        float4 rv = rr[i];
        r += rv.x + rv.y + rv.z + rv.w;
        float x[4] = {v.x, v.y, v.z, v.w};
        ushort_t h[4], m[4], l[4];
#pragma unroll
        for (int j = 0; j < 4; j++) {
            q += x[j] * x[j];
            h[j] = f2bf_rne(x[j]);
            float hf = __uint_as_float(((uint_t)h[j]) << 16);
            float r1 = x[j] - hf;
            m[j] = f2bf_rne(r1);
            float mf = __uint_as_float(((uint_t)m[j]) << 16);
            l[j] = f2bf_rne(r1 - mf);
        }
        size_t o = (size_t)k * (D >> 2) + i;
        ((ushort4*)Wh)[o] = make_ushort4(h[0], h[1], h[2], h[3]);
        ((ushort4*)Wm)[o] = make_ushort4(m[0], m[1], m[2], m[3]);
        ((ushort4*)Wl)[o] = make_ushort4(l[0], l[1], l[2], l[3]);
    }
    __shared__ float s1[128], s2[128];
    s1[t] = q; s2[t] = r; __syncthreads();
    for (int off = 64; off > 0; off >>= 1) {
        if (t < off) { s1[t] += s1[t + off]; s2[t] += s2[t + off]; }
        __syncthreads();
    }
    if (t == 0) { wsq[k] = s1[0]; rel_sum[k] = s2[0]; }
}

// --- kernel 3: 3-way-split bf16 MFMA distance GEMM + fused act/max/argmax ----
// dot = hh + hm + mh + hl + lh + mm  (ml/lm/ll dropped, ~2^-27 rel)
// LDS layout per plane, per 16-row group: [chunk16B c][row r] -> conflict-free
__global__ __launch_bounds__(256, 3) void k_gemm_act(
    const ushort_t* __restrict__ Xh, const ushort_t* __restrict__ Xm,
    const ushort_t* __restrict__ Xl,
    const ushort_t* __restrict__ Wh, const ushort_t* __restrict__ Wm,
    const ushort_t* __restrict__ Wl,
    const float* __restrict__ xsq, const float* __restrict__ wsq,
    const float* __restrict__ rs,
    float* __restrict__ pmax, int* __restrict__ pidx,
    int K, int D)
{
    // 6 planes x 8192 B (8 groups x [4 chunks][16 rows][16B])
    __shared__ char smem[49152];

    const int tid = threadIdx.x;
    const int wave = tid >> 6, lane = tid & 63;
    const int nk = K / BN;
    const int bx = blockIdx.x % nk, by = blockIdx.x / nk;
    const int b0 = by * BM, k0 = bx * BN;

    // staging lane map: row r = lane&15, chunk c = lane>>4  (LDS = c*256 + r*16)
    const int srow = wave * 32 + (lane & 15);
    const int scol = (lane >> 4) * 8;              // element offset in k-slice
    const size_t gx = (size_t)(b0 + srow) * D + scol;
    const size_t gw = (size_t)(k0 + srow) * D + scol;
    const size_t c1 = (size_t)16 * D;              // second 16-row group
    char* lb = smem + wave * 2048;                 // wave-uniform; HW adds lane*16

    const int wm = wave >> 1, wn = wave & 1;
    const int l15 = lane & 15, quad = lane >> 4;
    const int aoff = (wm * 4) * 1024 + quad * 256 + l15 * 16;
    const int boff = (wn * 4) * 1024 + quad * 256 + l15 * 16;

    f32x4 acc[4][4];
#pragma unroll
    for (int i = 0; i < 4; i++)
#pragma unroll
        for (int j = 0; j < 4; j++) acc[i][j] = (f32x4){0.f, 0.f, 0.f, 0.f};

    for (int kd = 0; kd < D; kd += 32) {
        gll16(Xh + gx + kd,      lb + 0);
        gll16(Xh + gx + c1 + kd, lb + 1024);
        gll16(Xm + gx + kd,      lb + 8192);
        gll16(Xm + gx + c1 + kd, lb + 8192 + 1024);
        gll16(Xl + gx + kd,      lb + 16384);
        gll16(Xl + gx + c1 + kd, lb + 16384 + 1024);
        gll16(Wh + gw + kd,      lb + 24576);
        gll16(Wh + gw + c1 + kd, lb + 24576 + 1024);
        gll16(Wm + gw + kd,      lb + 32768);
        gll16(Wm + gw + c1 + kd, lb + 32768 + 1024);
        gll16(Wl + gw + kd,      lb + 40960);
        gll16(Wl + gw + c1 + kd, lb + 40960 + 1024);
        __syncthreads();

        bf16x8 ah[4], am[4], al[4];
#pragma unroll
        for (int t = 0; t < 4; t++) {
            ah[t] = *(const bf16x8*)(smem + 0     + aoff + t * 1024);
            am[t] = *(const bf16x8*)(smem + 8192  + aoff + t * 1024);
            al[t] = *(const bf16x8*)(smem + 16384 + aoff + t * 1024);
        }
#pragma unroll
        for (int j = 0; j < 4; j++) {
            bf16x8 bh = *(const bf16x8*)(smem + 24576 + boff + j * 1024);
            bf16x8 bm = *(const bf16x8*)(smem + 32768 + boff + j * 1024);
            bf16x8 bl = *(const bf16x8*)(smem + 40960 + boff + j * 1024);
#pragma unroll
            for (int i = 0; i < 4; i++) {
                acc[i][j] = __builtin_amdgcn_mfma_f32_16x16x32_bf16(ah[i], bh, acc[i][j], 0, 0, 0);
                acc[i][j] = __builtin_amdgcn_mfma_f32_16x16x32_bf16(ah[i], bm, acc[i][j], 0, 0, 0);
                acc[i][j] = __builtin_amdgcn_mfma_f32_16x16x32_bf16(am[i], bh, acc[i][j], 0, 0, 0);
                acc[i][j] = __builtin_amdgcn_mfma_f32_16x16x32_bf16(ah[i], bl, acc[i][j], 0, 0, 0);
                acc[i][j] = __builtin_amdgcn_mfma_f32_16x16x32_bf16(al[i], bh, acc[i][j], 0, 0, 0);
                acc[i][j] = __builtin_amdgcn_mfma_f32_16x16x32_bf16(am[i], bm, acc[i][j], 0, 0, 0);
            }
        }
        __syncthreads();
    }

    // epilogue: act + per-row max/argmax (first-occurrence via k-tie rule)
    float rsv[4], wqv[4];
#pragma unroll
    for (int tn = 0; tn < 4; tn++) {
        int c = k0 + wn * 64 + tn * 16 + l15;
        rsv[tn] = rs[c]; wqv[tn] = wsq[c];
    }
    const float invD = 1.f / (float)D;
    float* redM = (float*)smem;          // [128][32], aliases tile LDS
    int*   redI = (int*)(smem + 16384);
#pragma unroll
    for (int tm = 0; tm < 4; tm++) {
#pragma unroll
        for (int r = 0; r < 4; r++) {
            int rowl = wm * 64 + tm * 16 + quad * 4 + r;
            float xq = xsq[b0 + rowl];
            float m = -1e30f; int mk = 0x7fffffff;
#pragma unroll
            for (int tn = 0; tn < 4; tn++) {
                float dot = acc[tm][tn][r];
                float dd = (xq + wqv[tn]) - 2.f * dot;
                float dw = dd * (rsv[tn] * invD);
                if (dw != dw) dw = 0.f;                       // isnan -> 0
                float act = rsv[tn] / ((rsv[tn] + dw) + 1e-7f);
                int kidx = k0 + wn * 64 + tn * 16 + l15;
                if (act > m || (act == m && kidx < mk)) { m = act; mk = kidx; }
            }
            redM[rowl * 32 + wn * 16 + l15] = m;
            redI[rowl * 32 + wn * 16 + l15] = mk;
        }
    }
    __syncthreads();
    if (tid < BM) {
        float m = -1e30f; int mk = 0x7fffffff;
#pragma unroll
        for (int t2 = 0; t2 < 32; t2++) {
            float v = redM[tid * 32 + t2]; int kv = redI[tid * 32 + t2];
            if (v > m || (v == m && kv < mk)) { m = v; mk = kv; }
        }
        pmax[(size_t)(b0 + tid) * nk + bx] = m;
        pidx[(size_t)(b0 + tid) * nk + bx] = mk;
    }
}

// ---- kernel 5: fused rowmax + segment sums (high and low) via atomics -------
__global__ __launch_bounds__(128) void k_segsum(
    const float* __restrict__ X,
    const float* __restrict__ pmax, const int* __restrict__ pidx, int nkt,
    float* __restrict__ cnt, float* __restrict__ cnt_l,
    float* __restrict__ sums, float* __restrict__ sums_l, int D)
{
    int b = blockIdx.x, t = threadIdx.x;
    __shared__ float sm[64];
    __shared__ int   si[64];
    __shared__ int s_node, s_hi;
    if (t < nkt) { sm[t] = pmax[(size_t)b * nkt + t]; si[t] = pidx[(size_t)b * nkt + t]; }
    __syncthreads();
    if (t == 0) {
        float m = -1e30f; int mk = 0x7fffffff;
        for (int i = 0; i < nkt; i++) {
            float v = sm[i]; int kv = si[i];
            if (v > m || (v == m && kv < mk)) { m = v; mk = kv; }
        }
        s_node = mk; s_hi = (m >= ATC) ? 1 : 0;
    }
    __syncthreads();
    int node = s_node, hi = s_hi;
    float* c = hi ? cnt : cnt_l;
    float* s = (hi ? sums : sums_l) + (size_t)node * D;
    if (t == 0) atomicAdd(c + node, 1.f);
    const float4* xv = (const float4*)(X + (size_t)b * D);
    for (int i = t; i < (D >> 2); i += 128) {
        float4 v = xv[i];
        atomicAdd(s + i * 4 + 0, v.x);
        atomicAdd(s + i * 4 + 1, v.y);
        atomicAdd(s + i * 4 + 2, v.z);
        atomicAdd(s + i * 4 + 3, v.w);
    }
}

// ---------------- kernel 6: per-node high-branch update (D == 512) -----------
__global__ __launch_bounds__(256) void k_high_update(
    const float* __restrict__ W, const float* __restrict__ MA,
    const float* __restrict__ REL, const float* __restrict__ NC,
    const float* __restrict__ cnt, const float* __restrict__ sums,
    float* __restrict__ outW, float* __restrict__ outMA,
    float* __restrict__ outREL, float* __restrict__ outNC,
    float* __restrict__ outLoss, int D, float invB)
{
    int k = blockIdx.x, t = threadIdx.x;
    size_t ro = (size_t)k * D;
    float c = cnt[k];
    __shared__ float sred[256];
    int t2 = t + 256;
    if (c > 0.f) {
        float mean0 = sums[ro + t]  / c;
        float mean1 = sums[ro + t2] / c;
        float w0 = W[ro + t],  w1 = W[ro + t2];
        float a0 = MA[ro + t], a1 = MA[ro + t2];
        float m0 = AC * fabsf(mean0 - w0) + OMAC * a0;
        float m1 = AC * fabsf(mean1 - w1) + OMAC * a1;

        sred[t] = fmaxf(m0, m1); __syncthreads();
        for (int off = 128; off > 0; off >>= 1) {
            if (t < off) sred[t] = fmaxf(sred[t], sred[t + off]);
            __syncthreads();
        }
        float mx = sred[0]; __syncthreads();
        sred[t] = fminf(m0, m1); __syncthreads();
        for (int off = 128; off > 0; off >>= 1) {
            if (t < off) sred[t] = fminf(sred[t], sred[t + off]);
            __syncthreads();
        }
        float mn = sred[0]; __syncthreads();
        sred[t] = m0 + m1; __syncthreads();
        for (int off = 128; off > 0; off >>= 1) {
            if (t < off) sred[t] += sred[t + off];
            __syncthreads();
        }
        float av = sred[0] / (float)D; __syncthreads();

        float scale = EPSC * (mx - mn);
        float r0 = 1.f / (1.f + expf((m0 - av) / scale));
        float r1 = 1.f / (1.f + expf((m1 - av) / scale));
        float d0 = LRC * (mean0 - w0), d1 = LRC * (mean1 - w1);

        outW[ro + t]  = w0 + d0;  outW[ro + t2]  = w1 + d1;
        outMA[ro + t] = m0;       outMA[ro + t2] = m1;
        outREL[ro + t] = r0;      outREL[ro + t2] = r1;

        sred[t] = d0 + d1; __syncthreads();
        for (int off = 128; off > 0; off >>= 1) {
            if (t < off) sred[t] += sred[t + off];
            __syncthreads();
        }
        if (t == 0) {
            atomicAdd(outLoss, sred[0] * invB);
            outNC[k] = 1.f;
        }
    } else {
        outW[ro + t]  = W[ro + t];   outW[ro + t2]  = W[ro + t2];
        outMA[ro + t] = MA[ro + t];  outMA[ro + t2] = MA[ro + t2];
        outREL[ro + t] = REL[ro + t]; outREL[ro + t2] = REL[ro + t2];
        if (t == 0) outNC[k] = NC[k];
    }
}

// ---------------- kernel 7: flags + prefix scan (single block) ---------------
__global__ __launch_bounds__(1024) void k_scan(
    const float* __restrict__ cnt_l, const float* __restrict__ outNC,
    int* __restrict__ low_ids, int* __restrict__ avail_ids,
    int* __restrict__ scal, int K)
{
    __shared__ int sL[1024], sA[1024];
    int t = threadIdx.x;
    int per = (K + 1023) / 1024;
    int base = t * per;
    int lv[8], av[8];
    int cl = 0, ca = 0;
    for (int j = 0; j < per; j++) {
        int k = base + j;
        int l = 0, a = 0;
        if (k < K) {
            l = (cnt_l[k] > 0.f) ? 1 : 0;
            a = (outNC[k] == 0.f) ? 1 : 0;
        }
        lv[j] = l; av[j] = a; cl += l; ca += a;
    }
    sL[t] = cl; sA[t] = ca; __syncthreads();
    for (int off = 1; off < 1024; off <<= 1) {
        int vL = (t >= off) ? sL[t - off] : 0;
        int vA = (t >= off) ? sA[t - off] : 0;
        __syncthreads();
        sL[t] += vL; sA[t] += vA;
        __syncthreads();
    }
    int totL = sL[1023], totA = sA[1023];
    int eL = sL[t] - cl, eA = sA[t] - ca;
    for (int j = 0; j < per; j++) {
        if (lv[j]) low_ids[eL++] = base + j;
        if (av[j]) avail_ids[eA++] = base + j;
    }
    if (t == 0) {
        scal[0] = totL;
        scal[1] = totA;
        scal[2] = (totL < totA) ? totL : totA;
    }
}

// ---------------- kernel 8: add-node scatter ---------------------------------
__global__ __launch_bounds__(128) void k_addnode(
    const float* __restrict__ cnt_l, const float* __restrict__ sums_l,
    const int* __restrict__ low_ids, const int* __restrict__ avail_ids,
    const int* __restrict__ scal,
    float* __restrict__ outW, float* __restrict__ outMA,
    float* __restrict__ outREL, float* __restrict__ outNC, int D)
{
    int r = blockIdx.x;
    int n_create = scal[2], n_new = scal[0];
    if (r >= n_create) return;
    int slot = avail_ids[r];
    int src  = low_ids[n_new - n_create + r];
    float c = cnt_l[src];
    size_t so = (size_t)src * D, to = (size_t)slot * D;
    for (int i = threadIdx.x; i < D; i += 128) {
        outW[to + i]  = sums_l[so + i] / c;
        outMA[to + i] = 0.f;
        outREL[to + i] = 1.f;
    }
    if (threadIdx.x == 0) outNC[slot] = 1.f;
}

// ---------------- launch -----------------------------------------------------
extern "C" void kernel_launch(void* const* d_in, const int* in_sizes, int n_in,
                              void* d_out, int out_size, void* d_ws, size_t ws_size,
                              hipStream_t stream) {
    const float* X   = (const float*)d_in[0];
    const float* W   = (const float*)d_in[1];
    const float* MA  = (const float*)d_in[2];
    const float* REL = (const float*)d_in[3];
    const float* NC  = (const float*)d_in[4];

    const int K = in_sizes[4];              // 4096
    const int D = in_sizes[1] / K;          // 512
    const int B = in_sizes[0] / D;          // 8192
    const int NKT = K / BN;                 // 32
    const size_t KD = (size_t)K * D;
    const size_t BD = (size_t)B * D;

    float* out = (float*)d_out;
    float* outLoss = out;
    float* outW   = out + 1;
    float* outMA  = out + 1 + KD;
    float* outREL = out + 1 + 2 * KD;
    float* outNC  = out + 1 + 3 * KD;

    float* wsf = (float*)d_ws;
    size_t off = 0;
    ushort_t* Xh = (ushort_t*)(wsf + off); off += BD / 2;
    ushort_t* Xm = (ushort_t*)(wsf + off); off += BD / 2;
    ushort_t* Xl = (ushort_t*)(wsf + off); off += BD / 2;
    ushort_t* Wh = (ushort_t*)(wsf + off); off += KD / 2;
    ushort_t* Wm = (ushort_t*)(wsf + off); off += KD / 2;
    ushort_t* Wl = (ushort_t*)(wsf + off); off += KD / 2;
    float* rel_sum = wsf + off; off += K;
    float* wsq     = wsf + off; off += K;
    float* xsq     = wsf + off; off += B;
    float* pmax    = wsf + off; off += (size_t)B * NKT;
    int*   pidx    = (int*)(wsf + off); off += (size_t)B * NKT;
    int*   low_ids   = (int*)(wsf + off); off += K;
    int*   avail_ids = (int*)(wsf + off); off += K;
    int*   scal    = (int*)(wsf + off); off += 16;
    float* zero_base = wsf + off;
    float* cnt   = wsf + off; off += K;
    float* cnt_l = wsf + off; off += K;
    float* sums   = wsf + off; off += KD;
    float* sums_l = wsf + off; off += KD;

    hipMemsetAsync(zero_base, 0, (2 * (size_t)K + 2 * KD) * sizeof(float), stream);
    hipMemsetAsync(outLoss, 0, sizeof(float), stream);

    k_prep_x<<<B, 128, 0, stream>>>(X, Xh, Xm, Xl, xsq, D);
    k_prep_w<<<K, 128, 0, stream>>>(W, REL, Wh, Wm, Wl, rel_sum, wsq, D);
    k_gemm_act<<<(B / BM) * (K / BN), 256, 0, stream>>>(Xh, Xm, Xl, Wh, Wm, Wl,
                                                        xsq, wsq, rel_sum,
                                                        pmax, pidx, K, D);
    k_segsum<<<B, 128, 0, stream>>>(X, pmax, pidx, NKT,
                                    cnt, cnt_l, sums, sums_l, D);
    k_high_update<<<K, 256, 0, stream>>>(W, MA, REL, NC, cnt, sums,
                                         outW, outMA, outREL, outNC, outLoss,
                                         D, 1.f / (float)B);
    k_scan<<<1, 1024, 0, stream>>>(cnt_l, outNC, low_ids, avail_ids, scal, K);
    k_addnode<<<K, 128, 0, stream>>>(cnt_l, sums_l, low_ids, avail_ids, scal,
                                     outW, outMA, outREL, outNC, D);
}

// Round 5
// 413.437 us; speedup vs baseline: 1.0707x; 1.0707x over previous
//
#include <hip/hip_runtime.h>

typedef unsigned short ushort_t;
typedef unsigned int uint_t;
typedef __bf16 bf16x8 __attribute__((ext_vector_type(8)));
typedef float f32x4 __attribute__((ext_vector_type(4)));

#define BM 128
#define BN 128

static constexpr float LRC  = 0.3f;
static constexpr float AC   = (float)(0.3 * 1e-4);          // LR*DSBETA
static constexpr float OMAC = (float)(1.0 - 0.3 * 1e-4);    // 1 - LR*DSBETA
static constexpr float EPSC = 0.01f;                        // EPS_DS
static constexpr float ATC  = 0.9f;                         // AT

__device__ __forceinline__ void gll16(const void* g, void* l) {
    __builtin_amdgcn_global_load_lds((__attribute__((address_space(1))) void*)g,
                                     (__attribute__((address_space(3))) void*)l,
                                     16, 0, 0);
}

__device__ __forceinline__ ushort_t f2bf_rne(float f) {
    uint_t u = __float_as_uint(f);
    uint_t r = u + 0x7fffu + ((u >> 16) & 1u);
    return (ushort_t)(r >> 16);
}

// -------- kernel A: fused prep: X and W 3-way bf16 splits + row stats --------
// blocks [0,B): X -> Xh/Xm/Xl + xsq ; blocks [B,B+K): W -> Wh/Wm/Wl + wsq/rel_sum
__global__ __launch_bounds__(128) void k_prep(
    const float* __restrict__ X, const float* __restrict__ W,
    const float* __restrict__ REL,
    ushort_t* __restrict__ Xh, ushort_t* __restrict__ Xm, ushort_t* __restrict__ Xl,
    ushort_t* __restrict__ Wh, ushort_t* __restrict__ Wm, ushort_t* __restrict__ Wl,
    float* __restrict__ xsq, float* __restrict__ wsq, float* __restrict__ rel_sum,
    int B, int D)
{
    int blk = blockIdx.x, t = threadIdx.x;
    bool isX = blk < B;
    int row = isX ? blk : blk - B;
    const float4* src = (const float4*)((isX ? X : W) + (size_t)row * D);
    const float4* rr  = isX ? nullptr : (const float4*)(REL + (size_t)row * D);
    ushort_t* H = isX ? Xh : Wh;
    ushort_t* M = isX ? Xm : Wm;
    ushort_t* L = isX ? Xl : Wl;
    float q = 0.f, r = 0.f;
    for (int i = t; i < (D >> 2); i += 128) {
        float4 v = src[i];
        if (!isX) { float4 rv = rr[i]; r += rv.x + rv.y + rv.z + rv.w; }
        float x[4] = {v.x, v.y, v.z, v.w};
        ushort_t h[4], m[4], l[4];
#pragma unroll
        for (int j = 0; j < 4; j++) {
            q += x[j] * x[j];
            h[j] = f2bf_rne(x[j]);
            float hf = __uint_as_float(((uint_t)h[j]) << 16);
            float r1 = x[j] - hf;
            m[j] = f2bf_rne(r1);
            float mf = __uint_as_float(((uint_t)m[j]) << 16);
            l[j] = f2bf_rne(r1 - mf);
        }
        size_t o = (size_t)row * (D >> 2) + i;
        ((ushort4*)H)[o] = make_ushort4(h[0], h[1], h[2], h[3]);
        ((ushort4*)M)[o] = make_ushort4(m[0], m[1], m[2], m[3]);
        ((ushort4*)L)[o] = make_ushort4(l[0], l[1], l[2], l[3]);
    }
    __shared__ float s1[128], s2[128];
    s1[t] = q; s2[t] = r; __syncthreads();
    for (int off = 64; off > 0; off >>= 1) {
        if (t < off) { s1[t] += s1[t + off]; s2[t] += s2[t + off]; }
        __syncthreads();
    }
    if (t == 0) {
        if (isX) xsq[row] = s1[0];
        else { wsq[row] = s1[0]; rel_sum[row] = s2[0]; }
    }
}

// --- kernel 3: 3-way-split bf16 MFMA distance GEMM + fused act/max/argmax ----
// dot = hh + hm + mh + hl + lh + mm  (ml/lm/ll dropped, ~2^-27 rel)
// Staging: lane p covers (row = p>>2, chunk = ((p&3) - (p>>3)) & 3) -> quad of
// lanes still covers contiguous 64B (coalesced), and fragment reads at index
// l15*4 + ((quad + (l15>>1)) & 3) are exactly conflict-free (each 8-lane phase
// covers 32 distinct banks).
__global__ __launch_bounds__(256, 2) void k_gemm_act(
    const ushort_t* __restrict__ Xh, const ushort_t* __restrict__ Xm,
    const ushort_t* __restrict__ Xl,
    const ushort_t* __restrict__ Wh, const ushort_t* __restrict__ Wm,
    const ushort_t* __restrict__ Wl,
    const float* __restrict__ xsq, const float* __restrict__ wsq,
    const float* __restrict__ rs,
    float* __restrict__ pmax, int* __restrict__ pidx,
    int K, int D)
{
    // 6 planes x 8192 B (8 groups of 16 rows x 1024 B)
    __shared__ char smem[49152];

    const int tid = threadIdx.x;
    const int wave = tid >> 6, lane = tid & 63;
    const int nk = K / BN;
    const int bx = blockIdx.x % nk, by = blockIdx.x / nk;
    const int b0 = by * BM, k0 = bx * BN;

    // staging lane map (swizzled chunk)
    const int srow = wave * 32 + (lane >> 2);
    const int schunk = ((lane & 3) - (lane >> 3)) & 3;
    const int scol = schunk * 8;                   // elements within 32-k slice
    const size_t gx = (size_t)(b0 + srow) * D + scol;
    const size_t gw = (size_t)(k0 + srow) * D + scol;
    const size_t c1 = (size_t)16 * D;              // second 16-row group
    char* lb = smem + wave * 2048;                 // wave-uniform; HW adds lane*16

    const int wm = wave >> 1, wn = wave & 1;
    const int l15 = lane & 15, quad = lane >> 4;
    // swizzled fragment read offset within a 1024B group
    const int roff = (l15 * 4 + ((quad + (l15 >> 1)) & 3)) * 16;
    const int aoff = (wm * 4) * 1024 + roff;
    const int boff = (wn * 4) * 1024 + roff;

    f32x4 acc[4][4];
#pragma unroll
    for (int i = 0; i < 4; i++)
#pragma unroll
        for (int j = 0; j < 4; j++) acc[i][j] = (f32x4){0.f, 0.f, 0.f, 0.f};

    for (int kd = 0; kd < D; kd += 32) {
        gll16(Xh + gx + kd,      lb + 0);
        gll16(Xh + gx + c1 + kd, lb + 1024);
        gll16(Xm + gx + kd,      lb + 8192);
        gll16(Xm + gx + c1 + kd, lb + 8192 + 1024);
        gll16(Xl + gx + kd,      lb + 16384);
        gll16(Xl + gx + c1 + kd, lb + 16384 + 1024);
        gll16(Wh + gw + kd,      lb + 24576);
        gll16(Wh + gw + c1 + kd, lb + 24576 + 1024);
        gll16(Wm + gw + kd,      lb + 32768);
        gll16(Wm + gw + c1 + kd, lb + 32768 + 1024);
        gll16(Wl + gw + kd,      lb + 40960);
        gll16(Wl + gw + c1 + kd, lb + 40960 + 1024);
        __syncthreads();

        bf16x8 ah[4], am[4], al[4];
#pragma unroll
        for (int t = 0; t < 4; t++) {
            ah[t] = *(const bf16x8*)(smem + 0     + aoff + t * 1024);
            am[t] = *(const bf16x8*)(smem + 8192  + aoff + t * 1024);
            al[t] = *(const bf16x8*)(smem + 16384 + aoff + t * 1024);
        }
#pragma unroll
        for (int j = 0; j < 4; j++) {
            bf16x8 bh = *(const bf16x8*)(smem + 24576 + boff + j * 1024);
            bf16x8 bm = *(const bf16x8*)(smem + 32768 + boff + j * 1024);
            bf16x8 bl = *(const bf16x8*)(smem + 40960 + boff + j * 1024);
#pragma unroll
            for (int i = 0; i < 4; i++) {
                acc[i][j] = __builtin_amdgcn_mfma_f32_16x16x32_bf16(ah[i], bh, acc[i][j], 0, 0, 0);
                acc[i][j] = __builtin_amdgcn_mfma_f32_16x16x32_bf16(ah[i], bm, acc[i][j], 0, 0, 0);
                acc[i][j] = __builtin_amdgcn_mfma_f32_16x16x32_bf16(am[i], bh, acc[i][j], 0, 0, 0);
                acc[i][j] = __builtin_amdgcn_mfma_f32_16x16x32_bf16(ah[i], bl, acc[i][j], 0, 0, 0);
                acc[i][j] = __builtin_amdgcn_mfma_f32_16x16x32_bf16(al[i], bh, acc[i][j], 0, 0, 0);
                acc[i][j] = __builtin_amdgcn_mfma_f32_16x16x32_bf16(am[i], bm, acc[i][j], 0, 0, 0);
            }
        }
        __syncthreads();
    }

    // epilogue: act + per-row max/argmax (first-occurrence via k-tie rule)
    float rsv[4], wqv[4];
#pragma unroll
    for (int tn = 0; tn < 4; tn++) {
        int c = k0 + wn * 64 + tn * 16 + l15;
        rsv[tn] = rs[c]; wqv[tn] = wsq[c];
    }
    const float invD = 1.f / (float)D;
    float* redM = (float*)smem;                    // [128][33] padded
    int*   redI = (int*)(smem + 17408);
#pragma unroll
    for (int tm = 0; tm < 4; tm++) {
#pragma unroll
        for (int r = 0; r < 4; r++) {
            int rowl = wm * 64 + tm * 16 + quad * 4 + r;
            float xq = xsq[b0 + rowl];
            float m = -1e30f; int mk = 0x7fffffff;
#pragma unroll
            for (int tn = 0; tn < 4; tn++) {
                float dot = acc[tm][tn][r];
                float dd = (xq + wqv[tn]) - 2.f * dot;
                float dw = dd * (rsv[tn] * invD);
                if (dw != dw) dw = 0.f;                       // isnan -> 0
                float act = rsv[tn] / ((rsv[tn] + dw) + 1e-7f);
                int kidx = k0 + wn * 64 + tn * 16 + l15;
                if (act > m || (act == m && kidx < mk)) { m = act; mk = kidx; }
            }
            redM[rowl * 33 + wn * 16 + l15] = m;
            redI[rowl * 33 + wn * 16 + l15] = mk;
        }
    }
    __syncthreads();
    if (tid < BM) {
        float m = -1e30f; int mk = 0x7fffffff;
#pragma unroll
        for (int t2 = 0; t2 < 32; t2++) {
            float v = redM[tid * 33 + t2]; int kv = redI[tid * 33 + t2];
            if (v > m || (v == m && kv < mk)) { m = v; mk = kv; }
        }
        pmax[(size_t)(b0 + tid) * nk + bx] = m;
        pidx[(size_t)(b0 + tid) * nk + bx] = mk;
    }
}

// ---- kernel 5: fused rowmax + segment sums (high and low) via atomics -------
__global__ __launch_bounds__(128) void k_segsum(
    const float* __restrict__ X,
    const float* __restrict__ pmax, const int* __restrict__ pidx, int nkt,
    float* __restrict__ cnt, float* __restrict__ cnt_l,
    float* __restrict__ sums, float* __restrict__ sums_l, int D)
{
    int b = blockIdx.x, t = threadIdx.x;
    __shared__ float sm[64];
    __shared__ int   si[64];
    __shared__ int s_node, s_hi;
    if (t < nkt) { sm[t] = pmax[(size_t)b * nkt + t]; si[t] = pidx[(size_t)b * nkt + t]; }
    __syncthreads();
    if (t == 0) {
        float m = -1e30f; int mk = 0x7fffffff;
        for (int i = 0; i < nkt; i++) {
            float v = sm[i]; int kv = si[i];
            if (v > m || (v == m && kv < mk)) { m = v; mk = kv; }
        }
        s_node = mk; s_hi = (m >= ATC) ? 1 : 0;
    }
    __syncthreads();
    int node = s_node, hi = s_hi;
    float* c = hi ? cnt : cnt_l;
    float* s = (hi ? sums : sums_l) + (size_t)node * D;
    if (t == 0) atomicAdd(c + node, 1.f);
    const float4* xv = (const float4*)(X + (size_t)b * D);
    for (int i = t; i < (D >> 2); i += 128) {
        float4 v = xv[i];
        atomicAdd(s + i * 4 + 0, v.x);
        atomicAdd(s + i * 4 + 1, v.y);
        atomicAdd(s + i * 4 + 2, v.z);
        atomicAdd(s + i * 4 + 3, v.w);
    }
}

// ---------------- kernel 6: per-node high-branch update (D == 512) -----------
__global__ __launch_bounds__(256) void k_high_update(
    const float* __restrict__ W, const float* __restrict__ MA,
    const float* __restrict__ REL, const float* __restrict__ NC,
    const float* __restrict__ cnt, const float* __restrict__ sums,
    float* __restrict__ outW, float* __restrict__ outMA,
    float* __restrict__ outREL, float* __restrict__ outNC,
    float* __restrict__ outLoss, int D, float invB)
{
    int k = blockIdx.x, t = threadIdx.x;
    size_t ro = (size_t)k * D;
    float c = cnt[k];
    __shared__ float sred[256];
    int t2 = t + 256;
    if (c > 0.f) {
        float mean0 = sums[ro + t]  / c;
        float mean1 = sums[ro + t2] / c;
        float w0 = W[ro + t],  w1 = W[ro + t2];
        float a0 = MA[ro + t], a1 = MA[ro + t2];
        float m0 = AC * fabsf(mean0 - w0) + OMAC * a0;
        float m1 = AC * fabsf(mean1 - w1) + OMAC * a1;

        sred[t] = fmaxf(m0, m1); __syncthreads();
        for (int off = 128; off > 0; off >>= 1) {
            if (t < off) sred[t] = fmaxf(sred[t], sred[t + off]);
            __syncthreads();
        }
        float mx = sred[0]; __syncthreads();
        sred[t] = fminf(m0, m1); __syncthreads();
        for (int off = 128; off > 0; off >>= 1) {
            if (t < off) sred[t] = fminf(sred[t], sred[t + off]);
            __syncthreads();
        }
        float mn = sred[0]; __syncthreads();
        sred[t] = m0 + m1; __syncthreads();
        for (int off = 128; off > 0; off >>= 1) {
            if (t < off) sred[t] += sred[t + off];
            __syncthreads();
        }
        float av = sred[0] / (float)D; __syncthreads();

        float scale = EPSC * (mx - mn);
        float r0 = 1.f / (1.f + expf((m0 - av) / scale));
        float r1 = 1.f / (1.f + expf((m1 - av) / scale));
        float d0 = LRC * (mean0 - w0), d1 = LRC * (mean1 - w1);

        outW[ro + t]  = w0 + d0;  outW[ro + t2]  = w1 + d1;
        outMA[ro + t] = m0;       outMA[ro + t2] = m1;
        outREL[ro + t] = r0;      outREL[ro + t2] = r1;

        sred[t] = d0 + d1; __syncthreads();
        for (int off = 128; off > 0; off >>= 1) {
            if (t < off) sred[t] += sred[t + off];
            __syncthreads();
        }
        if (t == 0) {
            atomicAdd(outLoss, sred[0] * invB);
            outNC[k] = 1.f;
        }
    } else {
        outW[ro + t]  = W[ro + t];   outW[ro + t2]  = W[ro + t2];
        outMA[ro + t] = MA[ro + t];  outMA[ro + t2] = MA[ro + t2];
        outREL[ro + t] = REL[ro + t]; outREL[ro + t2] = REL[ro + t2];
        if (t == 0) outNC[k] = NC[k];
    }
}

// ---------------- kernel 7: flags + prefix scan (single block) ---------------
__global__ __launch_bounds__(1024) void k_scan(
    const float* __restrict__ cnt_l, const float* __restrict__ outNC,
    int* __restrict__ low_ids, int* __restrict__ avail_ids,
    int* __restrict__ scal, int K)
{
    __shared__ int sL[1024], sA[1024];
    int t = threadIdx.x;
    int per = (K + 1023) / 1024;
    int base = t * per;
    int lv[8], av[8];
    int cl = 0, ca = 0;
    for (int j = 0; j < per; j++) {
        int k = base + j;
        int l = 0, a = 0;
        if (k < K) {
            l = (cnt_l[k] > 0.f) ? 1 : 0;
            a = (outNC[k] == 0.f) ? 1 : 0;
        }
        lv[j] = l; av[j] = a; cl += l; ca += a;
    }
    sL[t] = cl; sA[t] = ca; __syncthreads();
    for (int off = 1; off < 1024; off <<= 1) {
        int vL = (t >= off) ? sL[t - off] : 0;
        int vA = (t >= off) ? sA[t - off] : 0;
        __syncthreads();
        sL[t] += vL; sA[t] += vA;
        __syncthreads();
    }
    int totL = sL[1023], totA = sA[1023];
    int eL = sL[t] - cl, eA = sA[t] - ca;
    for (int j = 0; j < per; j++) {
        if (lv[j]) low_ids[eL++] = base + j;
        if (av[j]) avail_ids[eA++] = base + j;
    }
    if (t == 0) {
        scal[0] = totL;
        scal[1] = totA;
        scal[2] = (totL < totA) ? totL : totA;
    }
}

// ---------------- kernel 8: add-node scatter ---------------------------------
__global__ __launch_bounds__(128) void k_addnode(
    const float* __restrict__ cnt_l, const float* __restrict__ sums_l,
    const int* __restrict__ low_ids, const int* __restrict__ avail_ids,
    const int* __restrict__ scal,
    float* __restrict__ outW, float* __restrict__ outMA,
    float* __restrict__ outREL, float* __restrict__ outNC, int D)
{
    int r = blockIdx.x;
    int n_create = scal[2], n_new = scal[0];
    if (r >= n_create) return;
    int slot = avail_ids[r];
    int src  = low_ids[n_new - n_create + r];
    float c = cnt_l[src];
    size_t so = (size_t)src * D, to = (size_t)slot * D;
    for (int i = threadIdx.x; i < D; i += 128) {
        outW[to + i]  = sums_l[so + i] / c;
        outMA[to + i] = 0.f;
        outREL[to + i] = 1.f;
    }
    if (threadIdx.x == 0) outNC[slot] = 1.f;
}

// ---------------- launch -----------------------------------------------------
extern "C" void kernel_launch(void* const* d_in, const int* in_sizes, int n_in,
                              void* d_out, int out_size, void* d_ws, size_t ws_size,
                              hipStream_t stream) {
    const float* X   = (const float*)d_in[0];
    const float* W   = (const float*)d_in[1];
    const float* MA  = (const float*)d_in[2];
    const float* REL = (const float*)d_in[3];
    const float* NC  = (const float*)d_in[4];

    const int K = in_sizes[4];              // 4096
    const int D = in_sizes[1] / K;          // 512
    const int B = in_sizes[0] / D;          // 8192
    const int NKT = K / BN;                 // 32
    const size_t KD = (size_t)K * D;
    const size_t BD = (size_t)B * D;

    float* out = (float*)d_out;
    float* outLoss = out;
    float* outW   = out + 1;
    float* outMA  = out + 1 + KD;
    float* outREL = out + 1 + 2 * KD;
    float* outNC  = out + 1 + 3 * KD;

    float* wsf = (float*)d_ws;
    size_t off = 0;
    ushort_t* Xh = (ushort_t*)(wsf + off); off += BD / 2;
    ushort_t* Xm = (ushort_t*)(wsf + off); off += BD / 2;
    ushort_t* Xl = (ushort_t*)(wsf + off); off += BD / 2;
    ushort_t* Wh = (ushort_t*)(wsf + off); off += KD / 2;
    ushort_t* Wm = (ushort_t*)(wsf + off); off += KD / 2;
    ushort_t* Wl = (ushort_t*)(wsf + off); off += KD / 2;
    float* rel_sum = wsf + off; off += K;
    float* wsq     = wsf + off; off += K;
    float* xsq     = wsf + off; off += B;
    float* pmax    = wsf + off; off += (size_t)B * NKT;
    int*   pidx    = (int*)(wsf + off); off += (size_t)B * NKT;
    int*   low_ids   = (int*)(wsf + off); off += K;
    int*   avail_ids = (int*)(wsf + off); off += K;
    int*   scal    = (int*)(wsf + off); off += 16;
    float* zero_base = wsf + off;
    float* cnt   = wsf + off; off += K;
    float* cnt_l = wsf + off; off += K;
    float* sums   = wsf + off; off += KD;
    float* sums_l = wsf + off; off += KD;

    hipMemsetAsync(zero_base, 0, (2 * (size_t)K + 2 * KD) * sizeof(float), stream);
    hipMemsetAsync(outLoss, 0, sizeof(float), stream);

    k_prep<<<B + K, 128, 0, stream>>>(X, W, REL, Xh, Xm, Xl, Wh, Wm, Wl,
                                      xsq, wsq, rel_sum, B, D);
    k_gemm_act<<<(B / BM) * (K / BN), 256, 0, stream>>>(Xh, Xm, Xl, Wh, Wm, Wl,
                                                        xsq, wsq, rel_sum,
                                                        pmax, pidx, K, D);
    k_segsum<<<B, 128, 0, stream>>>(X, pmax, pidx, NKT,
                                    cnt, cnt_l, sums, sums_l, D);
    k_high_update<<<K, 256, 0, stream>>>(W, MA, REL, NC, cnt, sums,
                                         outW, outMA, outREL, outNC, outLoss,
                                         D, 1.f / (float)B);
    k_scan<<<1, 1024, 0, stream>>>(cnt_l, outNC, low_ids, avail_ids, scal, K);
    k_addnode<<<K, 128, 0, stream>>>(cnt_l, sums_l, low_ids, avail_ids, scal,
                                     outW, outMA, outREL, outNC, D);
}

// Round 6
// 374.509 us; speedup vs baseline: 1.1820x; 1.1039x over previous
//
#include <hip/hip_runtime.h>

typedef unsigned short ushort_t;
typedef unsigned int uint_t;
typedef __bf16 bf16x8 __attribute__((ext_vector_type(8)));
typedef float f32x4 __attribute__((ext_vector_type(4)));

#define BM 128
#define BN 128

static constexpr float LRC  = 0.3f;
static constexpr float AC   = (float)(0.3 * 1e-4);          // LR*DSBETA
static constexpr float OMAC = (float)(1.0 - 0.3 * 1e-4);    // 1 - LR*DSBETA
static constexpr float EPSC = 0.01f;                        // EPS_DS
static constexpr float ATC  = 0.9f;                         // AT

__device__ __forceinline__ void gll16(const void* g, void* l) {
    __builtin_amdgcn_global_load_lds((__attribute__((address_space(1))) void*)g,
                                     (__attribute__((address_space(3))) void*)l,
                                     16, 0, 0);
}

__device__ __forceinline__ ushort_t f2bf_rne(float f) {
    uint_t u = __float_as_uint(f);
    uint_t r = u + 0x7fffu + ((u >> 16) & 1u);
    return (ushort_t)(r >> 16);
}

// -------- kernel A: fused prep: X and W 3-way bf16 splits + row stats --------
__global__ __launch_bounds__(128) void k_prep(
    const float* __restrict__ X, const float* __restrict__ W,
    const float* __restrict__ REL,
    ushort_t* __restrict__ Xh, ushort_t* __restrict__ Xm, ushort_t* __restrict__ Xl,
    ushort_t* __restrict__ Wh, ushort_t* __restrict__ Wm, ushort_t* __restrict__ Wl,
    float* __restrict__ xsq, float* __restrict__ wsq, float* __restrict__ rel_sum,
    int B, int D)
{
    int blk = blockIdx.x, t = threadIdx.x;
    bool isX = blk < B;
    int row = isX ? blk : blk - B;
    const float4* src = (const float4*)((isX ? X : W) + (size_t)row * D);
    const float4* rr  = isX ? nullptr : (const float4*)(REL + (size_t)row * D);
    ushort_t* H = isX ? Xh : Wh;
    ushort_t* M = isX ? Xm : Wm;
    ushort_t* L = isX ? Xl : Wl;
    float q = 0.f, r = 0.f;
    for (int i = t; i < (D >> 2); i += 128) {
        float4 v = src[i];
        if (!isX) { float4 rv = rr[i]; r += rv.x + rv.y + rv.z + rv.w; }
        float x[4] = {v.x, v.y, v.z, v.w};
        ushort_t h[4], m[4], l[4];
#pragma unroll
        for (int j = 0; j < 4; j++) {
            q += x[j] * x[j];
            h[j] = f2bf_rne(x[j]);
            float hf = __uint_as_float(((uint_t)h[j]) << 16);
            float r1 = x[j] - hf;
            m[j] = f2bf_rne(r1);
            float mf = __uint_as_float(((uint_t)m[j]) << 16);
            l[j] = f2bf_rne(r1 - mf);
        }
        size_t o = (size_t)row * (D >> 2) + i;
        ((ushort4*)H)[o] = make_ushort4(h[0], h[1], h[2], h[3]);
        ((ushort4*)M)[o] = make_ushort4(m[0], m[1], m[2], m[3]);
        ((ushort4*)L)[o] = make_ushort4(l[0], l[1], l[2], l[3]);
    }
    __shared__ float s1[128], s2[128];
    s1[t] = q; s2[t] = r; __syncthreads();
    for (int off = 64; off > 0; off >>= 1) {
        if (t < off) { s1[t] += s1[t + off]; s2[t] += s2[t + off]; }
        __syncthreads();
    }
    if (t == 0) {
        if (isX) xsq[row] = s1[0];
        else { wsq[row] = s1[0]; rel_sum[row] = s2[0]; }
    }
}

// --- kernel 3: 3-way-split bf16 MFMA distance GEMM + fused act/max/argmax ----
// (unchanged from R5: conflict-free swizzled LDS, 198 us, MfmaUtil ~47%)
__global__ __launch_bounds__(256, 2) void k_gemm_act(
    const ushort_t* __restrict__ Xh, const ushort_t* __restrict__ Xm,
    const ushort_t* __restrict__ Xl,
    const ushort_t* __restrict__ Wh, const ushort_t* __restrict__ Wm,
    const ushort_t* __restrict__ Wl,
    const float* __restrict__ xsq, const float* __restrict__ wsq,
    const float* __restrict__ rs,
    float* __restrict__ pmax, int* __restrict__ pidx,
    int K, int D)
{
    __shared__ char smem[49152];

    const int tid = threadIdx.x;
    const int wave = tid >> 6, lane = tid & 63;
    const int nk = K / BN;
    const int bx = blockIdx.x % nk, by = blockIdx.x / nk;
    const int b0 = by * BM, k0 = bx * BN;

    const int srow = wave * 32 + (lane >> 2);
    const int schunk = ((lane & 3) - (lane >> 3)) & 3;
    const int scol = schunk * 8;
    const size_t gx = (size_t)(b0 + srow) * D + scol;
    const size_t gw = (size_t)(k0 + srow) * D + scol;
    const size_t c1 = (size_t)16 * D;
    char* lb = smem + wave * 2048;

    const int wm = wave >> 1, wn = wave & 1;
    const int l15 = lane & 15, quad = lane >> 4;
    const int roff = (l15 * 4 + ((quad + (l15 >> 1)) & 3)) * 16;
    const int aoff = (wm * 4) * 1024 + roff;
    const int boff = (wn * 4) * 1024 + roff;

    f32x4 acc[4][4];
#pragma unroll
    for (int i = 0; i < 4; i++)
#pragma unroll
        for (int j = 0; j < 4; j++) acc[i][j] = (f32x4){0.f, 0.f, 0.f, 0.f};

    for (int kd = 0; kd < D; kd += 32) {
        gll16(Xh + gx + kd,      lb + 0);
        gll16(Xh + gx + c1 + kd, lb + 1024);
        gll16(Xm + gx + kd,      lb + 8192);
        gll16(Xm + gx + c1 + kd, lb + 8192 + 1024);
        gll16(Xl + gx + kd,      lb + 16384);
        gll16(Xl + gx + c1 + kd, lb + 16384 + 1024);
        gll16(Wh + gw + kd,      lb + 24576);
        gll16(Wh + gw + c1 + kd, lb + 24576 + 1024);
        gll16(Wm + gw + kd,      lb + 32768);
        gll16(Wm + gw + c1 + kd, lb + 32768 + 1024);
        gll16(Wl + gw + kd,      lb + 40960);
        gll16(Wl + gw + c1 + kd, lb + 40960 + 1024);
        __syncthreads();

        bf16x8 ah[4], am[4], al[4];
#pragma unroll
        for (int t = 0; t < 4; t++) {
            ah[t] = *(const bf16x8*)(smem + 0     + aoff + t * 1024);
            am[t] = *(const bf16x8*)(smem + 8192  + aoff + t * 1024);
            al[t] = *(const bf16x8*)(smem + 16384 + aoff + t * 1024);
        }
#pragma unroll
        for (int j = 0; j < 4; j++) {
            bf16x8 bh = *(const bf16x8*)(smem + 24576 + boff + j * 1024);
            bf16x8 bm = *(const bf16x8*)(smem + 32768 + boff + j * 1024);
            bf16x8 bl = *(const bf16x8*)(smem + 40960 + boff + j * 1024);
#pragma unroll
            for (int i = 0; i < 4; i++) {
                acc[i][j] = __builtin_amdgcn_mfma_f32_16x16x32_bf16(ah[i], bh, acc[i][j], 0, 0, 0);
                acc[i][j] = __builtin_amdgcn_mfma_f32_16x16x32_bf16(ah[i], bm, acc[i][j], 0, 0, 0);
                acc[i][j] = __builtin_amdgcn_mfma_f32_16x16x32_bf16(am[i], bh, acc[i][j], 0, 0, 0);
                acc[i][j] = __builtin_amdgcn_mfma_f32_16x16x32_bf16(ah[i], bl, acc[i][j], 0, 0, 0);
                acc[i][j] = __builtin_amdgcn_mfma_f32_16x16x32_bf16(al[i], bh, acc[i][j], 0, 0, 0);
                acc[i][j] = __builtin_amdgcn_mfma_f32_16x16x32_bf16(am[i], bm, acc[i][j], 0, 0, 0);
            }
        }
        __syncthreads();
    }

    float rsv[4], wqv[4];
#pragma unroll
    for (int tn = 0; tn < 4; tn++) {
        int c = k0 + wn * 64 + tn * 16 + l15;
        rsv[tn] = rs[c]; wqv[tn] = wsq[c];
    }
    const float invD = 1.f / (float)D;
    float* redM = (float*)smem;                    // [128][33] padded
    int*   redI = (int*)(smem + 17408);
#pragma unroll
    for (int tm = 0; tm < 4; tm++) {
#pragma unroll
        for (int r = 0; r < 4; r++) {
            int rowl = wm * 64 + tm * 16 + quad * 4 + r;
            float xq = xsq[b0 + rowl];
            float m = -1e30f; int mk = 0x7fffffff;
#pragma unroll
            for (int tn = 0; tn < 4; tn++) {
                float dot = acc[tm][tn][r];
                float dd = (xq + wqv[tn]) - 2.f * dot;
                float dw = dd * (rsv[tn] * invD);
                if (dw != dw) dw = 0.f;
                float act = rsv[tn] / ((rsv[tn] + dw) + 1e-7f);
                int kidx = k0 + wn * 64 + tn * 16 + l15;
                if (act > m || (act == m && kidx < mk)) { m = act; mk = kidx; }
            }
            redM[rowl * 33 + wn * 16 + l15] = m;
            redI[rowl * 33 + wn * 16 + l15] = mk;
        }
    }
    __syncthreads();
    if (tid < BM) {
        float m = -1e30f; int mk = 0x7fffffff;
#pragma unroll
        for (int t2 = 0; t2 < 32; t2++) {
            float v = redM[tid * 33 + t2]; int kv = redI[tid * 33 + t2];
            if (v > m || (v == m && kv < mk)) { m = v; mk = kv; }
        }
        pmax[(size_t)(b0 + tid) * nk + bx] = m;
        pidx[(size_t)(b0 + tid) * nk + bx] = mk;
    }
}

// ---- kernel 4: BMU per sample + rank assignment (int atomics) ---------------
__global__ __launch_bounds__(256) void k_bmu(
    const float* __restrict__ pmax, const int* __restrict__ pidx, int nkt,
    int* __restrict__ cnt, int* __restrict__ cnt_l,
    int* __restrict__ idxb, int* __restrict__ rankb, int* __restrict__ highb,
    int B)
{
    int b = blockIdx.x * 256 + threadIdx.x;
    if (b >= B) return;
    float m = -1e30f; int mk = 0x7fffffff;
    for (int t = 0; t < nkt; t++) {
        float v = pmax[(size_t)b * nkt + t];
        int kv = pidx[(size_t)b * nkt + t];
        if (v > m || (v == m && kv < mk)) { m = v; mk = kv; }
    }
    int hi = (m >= ATC) ? 1 : 0;
    int rank = atomicAdd((hi ? cnt : cnt_l) + mk, 1);
    idxb[b] = mk; rankb[b] = rank; highb[b] = hi;
}

// ---- kernel 5: offsets (prefix sums) + low/avail compaction (one block) -----
__global__ __launch_bounds__(1024) void k_offsets(
    const int* __restrict__ cnt, const int* __restrict__ cnt_l,
    const float* __restrict__ NC,
    int* __restrict__ offs_h, int* __restrict__ offs_l,
    int* __restrict__ low_ids, int* __restrict__ avail_ids,
    int* __restrict__ scal, int K)
{
    __shared__ int sA[1024], sB[1024];
    int t = threadIdx.x;
    int per = (K + 1023) / 1024;     // 4
    int base = t * per;
    // ---- pass 1: exclusive offsets for high and low lists ----
    int ch[8], cl[8]; int sh = 0, sl = 0;
    for (int j = 0; j < per; j++) {
        int k = base + j;
        int a = (k < K) ? cnt[k] : 0;
        int b = (k < K) ? cnt_l[k] : 0;
        ch[j] = a; cl[j] = b; sh += a; sl += b;
    }
    sA[t] = sh; sB[t] = sl; __syncthreads();
    for (int off = 1; off < 1024; off <<= 1) {
        int vA = (t >= off) ? sA[t - off] : 0;
        int vB = (t >= off) ? sB[t - off] : 0;
        __syncthreads();
        sA[t] += vA; sB[t] += vB;
        __syncthreads();
    }
    int eh = sA[t] - sh, el = sB[t] - sl;
    for (int j = 0; j < per; j++) {
        int k = base + j;
        if (k < K) { offs_h[k] = eh; offs_l[k] = el; }
        eh += ch[j]; el += cl[j];
    }
    __syncthreads();
    // ---- pass 2: low_valid / avail compaction ----
    int lv[8], av[8]; int cL = 0, cA = 0;
    for (int j = 0; j < per; j++) {
        int k = base + j;
        int l = 0, a = 0;
        if (k < K) {
            l = (cl[j] > 0) ? 1 : 0;
            float nc1 = (ch[j] > 0) ? 1.f : NC[k];
            a = (nc1 == 0.f) ? 1 : 0;
        }
        lv[j] = l; av[j] = a; cL += l; cA += a;
    }
    sA[t] = cL; sB[t] = cA; __syncthreads();
    for (int off = 1; off < 1024; off <<= 1) {
        int vA = (t >= off) ? sA[t - off] : 0;
        int vB = (t >= off) ? sB[t - off] : 0;
        __syncthreads();
        sA[t] += vA; sB[t] += vB;
        __syncthreads();
    }
    int totL = sA[1023], totA = sB[1023];
    int eL = sA[t] - cL, eA = sB[t] - cA;
    for (int j = 0; j < per; j++) {
        if (lv[j]) low_ids[eL++] = base + j;
        if (av[j]) avail_ids[eA++] = base + j;
    }
    if (t == 0) {
        scal[0] = totL;
        scal[1] = totA;
        scal[2] = (totL < totA) ? totL : totA;
    }
}

// ---- kernel 6: scatter sample ids into per-node lists -----------------------
__global__ __launch_bounds__(256) void k_scatter(
    const int* __restrict__ idxb, const int* __restrict__ rankb,
    const int* __restrict__ highb,
    const int* __restrict__ offs_h, const int* __restrict__ offs_l,
    int* __restrict__ list_h, int* __restrict__ list_l, int B)
{
    int b = blockIdx.x * 256 + threadIdx.x;
    if (b >= B) return;
    int node = idxb[b];
    if (highb[b]) list_h[offs_h[node] + rankb[b]] = b;
    else          list_l[offs_l[node] + rankb[b]] = b;
}

// ---- kernel 7: per-node high-branch update (list gather, D == 512) ----------
__global__ __launch_bounds__(256) void k_high_update(
    const float* __restrict__ X,
    const float* __restrict__ W, const float* __restrict__ MA,
    const float* __restrict__ REL, const float* __restrict__ NC,
    const int* __restrict__ cnt, const int* __restrict__ offs_h,
    const int* __restrict__ list_h,
    float* __restrict__ outW, float* __restrict__ outMA,
    float* __restrict__ outREL, float* __restrict__ outNC,
    float* __restrict__ outLoss, int D, float invB)
{
    int k = blockIdx.x, t = threadIdx.x;
    size_t ro = (size_t)k * D;
    int n = cnt[k];
    int t2 = t + 256;
    __shared__ float rbuf[12];
    if (n > 0) {
        float s0 = 0.f, s1 = 0.f;
        int base = offs_h[k];
        for (int i = 0; i < n; i++) {
            int b = list_h[base + i];
            const float* xr = X + (size_t)b * D;
            s0 += xr[t]; s1 += xr[t2];
        }
        float fn = (float)n;
        float mean0 = s0 / fn, mean1 = s1 / fn;
        float w0 = W[ro + t],  w1 = W[ro + t2];
        float a0 = MA[ro + t], a1 = MA[ro + t2];
        float m0 = AC * fabsf(mean0 - w0) + OMAC * a0;
        float m1 = AC * fabsf(mean1 - w1) + OMAC * a1;

        float vmax = fmaxf(m0, m1), vmin = fminf(m0, m1), vsum = m0 + m1;
#pragma unroll
        for (int o = 1; o < 64; o <<= 1) {
            vmax = fmaxf(vmax, __shfl_xor(vmax, o));
            vmin = fminf(vmin, __shfl_xor(vmin, o));
            vsum += __shfl_xor(vsum, o);
        }
        int wv = t >> 6, ln = t & 63;
        if (ln == 0) { rbuf[wv] = vmax; rbuf[4 + wv] = vmin; rbuf[8 + wv] = vsum; }
        __syncthreads();
        float mx = fmaxf(fmaxf(rbuf[0], rbuf[1]), fmaxf(rbuf[2], rbuf[3]));
        float mn = fminf(fminf(rbuf[4], rbuf[5]), fminf(rbuf[6], rbuf[7]));
        float av = (rbuf[8] + rbuf[9] + rbuf[10] + rbuf[11]) / (float)D;

        float scale = EPSC * (mx - mn);
        float r0 = 1.f / (1.f + expf((m0 - av) / scale));
        float r1 = 1.f / (1.f + expf((m1 - av) / scale));
        float d0 = LRC * (mean0 - w0), d1 = LRC * (mean1 - w1);

        outW[ro + t]  = w0 + d0;  outW[ro + t2]  = w1 + d1;
        outMA[ro + t] = m0;       outMA[ro + t2] = m1;
        outREL[ro + t] = r0;      outREL[ro + t2] = r1;

        float ls = d0 + d1;
#pragma unroll
        for (int o = 1; o < 64; o <<= 1) ls += __shfl_xor(ls, o);
        __syncthreads();
        if (ln == 0) rbuf[wv] = ls;
        __syncthreads();
        if (t == 0) {
            atomicAdd(outLoss, (rbuf[0] + rbuf[1] + rbuf[2] + rbuf[3]) * invB);
            outNC[k] = 1.f;
        }
    } else {
        outW[ro + t]  = W[ro + t];   outW[ro + t2]  = W[ro + t2];
        outMA[ro + t] = MA[ro + t];  outMA[ro + t2] = MA[ro + t2];
        outREL[ro + t] = REL[ro + t]; outREL[ro + t2] = REL[ro + t2];
        if (t == 0) outNC[k] = NC[k];
    }
}

// ---- kernel 8: add-node scatter (list gather means) -------------------------
__global__ __launch_bounds__(256) void k_addnode(
    const float* __restrict__ X,
    const int* __restrict__ cnt_l, const int* __restrict__ offs_l,
    const int* __restrict__ list_l,
    const int* __restrict__ low_ids, const int* __restrict__ avail_ids,
    const int* __restrict__ scal,
    float* __restrict__ outW, float* __restrict__ outMA,
    float* __restrict__ outREL, float* __restrict__ outNC, int D)
{
    int r = blockIdx.x;
    int n_create = scal[2], n_new = scal[0];
    if (r >= n_create) return;
    int slot = avail_ids[r];
    int src  = low_ids[n_new - n_create + r];
    int n = cnt_l[src];
    int t = threadIdx.x, t2 = t + 256;
    float s0 = 0.f, s1 = 0.f;
    int base = offs_l[src];
    for (int i = 0; i < n; i++) {
        int b = list_l[base + i];
        const float* xr = X + (size_t)b * D;
        s0 += xr[t]; s1 += xr[t2];
    }
    float fn = (float)n;
    size_t to = (size_t)slot * D;
    outW[to + t]  = s0 / fn;  outW[to + t2]  = s1 / fn;
    outMA[to + t] = 0.f;      outMA[to + t2] = 0.f;
    outREL[to + t] = 1.f;     outREL[to + t2] = 1.f;
    if (t == 0) outNC[slot] = 1.f;
}

// ---------------- launch -----------------------------------------------------
extern "C" void kernel_launch(void* const* d_in, const int* in_sizes, int n_in,
                              void* d_out, int out_size, void* d_ws, size_t ws_size,
                              hipStream_t stream) {
    const float* X   = (const float*)d_in[0];
    const float* W   = (const float*)d_in[1];
    const float* MA  = (const float*)d_in[2];
    const float* REL = (const float*)d_in[3];
    const float* NC  = (const float*)d_in[4];

    const int K = in_sizes[4];              // 4096
    const int D = in_sizes[1] / K;          // 512
    const int B = in_sizes[0] / D;          // 8192
    const int NKT = K / BN;                 // 32
    const size_t KD = (size_t)K * D;
    const size_t BD = (size_t)B * D;

    float* out = (float*)d_out;
    float* outLoss = out;
    float* outW   = out + 1;
    float* outMA  = out + 1 + KD;
    float* outREL = out + 1 + 2 * KD;
    float* outNC  = out + 1 + 3 * KD;

    float* wsf = (float*)d_ws;
    size_t off = 0;
    ushort_t* Xh = (ushort_t*)(wsf + off); off += BD / 2;
    ushort_t* Xm = (ushort_t*)(wsf + off); off += BD / 2;
    ushort_t* Xl = (ushort_t*)(wsf + off); off += BD / 2;
    ushort_t* Wh = (ushort_t*)(wsf + off); off += KD / 2;
    ushort_t* Wm = (ushort_t*)(wsf + off); off += KD / 2;
    ushort_t* Wl = (ushort_t*)(wsf + off); off += KD / 2;
    float* rel_sum = wsf + off; off += K;
    float* wsq     = wsf + off; off += K;
    float* xsq     = wsf + off; off += B;
    float* pmax    = wsf + off; off += (size_t)B * NKT;
    int*   pidx    = (int*)(wsf + off); off += (size_t)B * NKT;
    int*   idxb    = (int*)(wsf + off); off += B;
    int*   rankb   = (int*)(wsf + off); off += B;
    int*   highb   = (int*)(wsf + off); off += B;
    int*   list_h  = (int*)(wsf + off); off += B;
    int*   list_l  = (int*)(wsf + off); off += B;
    int*   offs_h  = (int*)(wsf + off); off += K;
    int*   offs_l  = (int*)(wsf + off); off += K;
    int*   low_ids   = (int*)(wsf + off); off += K;
    int*   avail_ids = (int*)(wsf + off); off += K;
    int*   scal    = (int*)(wsf + off); off += 16;
    int*   cnt     = (int*)(wsf + off); off += K;
    int*   cnt_l   = (int*)(wsf + off); off += K;

    hipMemsetAsync(cnt, 0, 2 * (size_t)K * sizeof(int), stream);
    hipMemsetAsync(outLoss, 0, sizeof(float), stream);

    k_prep<<<B + K, 128, 0, stream>>>(X, W, REL, Xh, Xm, Xl, Wh, Wm, Wl,
                                      xsq, wsq, rel_sum, B, D);
    k_gemm_act<<<(B / BM) * (K / BN), 256, 0, stream>>>(Xh, Xm, Xl, Wh, Wm, Wl,
                                                        xsq, wsq, rel_sum,
                                                        pmax, pidx, K, D);
    k_bmu<<<(B + 255) / 256, 256, 0, stream>>>(pmax, pidx, NKT, cnt, cnt_l,
                                               idxb, rankb, highb, B);
    k_offsets<<<1, 1024, 0, stream>>>(cnt, cnt_l, NC, offs_h, offs_l,
                                      low_ids, avail_ids, scal, K);
    k_scatter<<<(B + 255) / 256, 256, 0, stream>>>(idxb, rankb, highb,
                                                   offs_h, offs_l,
                                                   list_h, list_l, B);
    k_high_update<<<K, 256, 0, stream>>>(X, W, MA, REL, NC, cnt, offs_h, list_h,
                                         outW, outMA, outREL, outNC, outLoss,
                                         D, 1.f / (float)B);
    k_addnode<<<K, 256, 0, stream>>>(X, cnt_l, offs_l, list_l,
                                     low_ids, avail_ids, scal,
                                     outW, outMA, outREL, outNC, D);
}

// Round 7
// 265.849 us; speedup vs baseline: 1.6651x; 1.4087x over previous
//
#include <hip/hip_runtime.h>

typedef unsigned short ushort_t;
typedef unsigned int uint_t;
typedef __bf16 bf16x8 __attribute__((ext_vector_type(8)));
typedef float f32x4 __attribute__((ext_vector_type(4)));

#define BM 128
#define BN 128

static constexpr float LRC  = 0.3f;
static constexpr float AC   = (float)(0.3 * 1e-4);          // LR*DSBETA
static constexpr float OMAC = (float)(1.0 - 0.3 * 1e-4);    // 1 - LR*DSBETA
static constexpr float EPSC = 0.01f;                        // EPS_DS
static constexpr float ATC  = 0.9f;                         // AT
static constexpr float DELTA = 5e-4f;   // screen margin, ~33 sigma of hh act err

__device__ __forceinline__ void gll16(const void* g, void* l) {
    __builtin_amdgcn_global_load_lds((__attribute__((address_space(1))) void*)g,
                                     (__attribute__((address_space(3))) void*)l,
                                     16, 0, 0);
}

__device__ __forceinline__ ushort_t f2bf_rne(float f) {
    uint_t u = __float_as_uint(f);
    uint_t r = u + 0x7fffu + ((u >> 16) & 1u);
    return (ushort_t)(r >> 16);
}

// -------- kernel A: prep: X/W -> hi bf16 plane + row stats -------------------
__global__ __launch_bounds__(128) void k_prep(
    const float* __restrict__ X, const float* __restrict__ W,
    const float* __restrict__ REL,
    ushort_t* __restrict__ Xh, ushort_t* __restrict__ Wh,
    float* __restrict__ xsq, float* __restrict__ wsq, float* __restrict__ rel_sum,
    int B, int D)
{
    int blk = blockIdx.x, t = threadIdx.x;
    bool isX = blk < B;
    int row = isX ? blk : blk - B;
    const float4* src = (const float4*)((isX ? X : W) + (size_t)row * D);
    const float4* rr  = isX ? nullptr : (const float4*)(REL + (size_t)row * D);
    ushort_t* H = isX ? Xh : Wh;
    float q = 0.f, r = 0.f;
    for (int i = t; i < (D >> 2); i += 128) {
        float4 v = src[i];
        if (!isX) { float4 rv = rr[i]; r += rv.x + rv.y + rv.z + rv.w; }
        float x[4] = {v.x, v.y, v.z, v.w};
        ushort_t h[4];
#pragma unroll
        for (int j = 0; j < 4; j++) { q += x[j] * x[j]; h[j] = f2bf_rne(x[j]); }
        ((ushort4*)H)[(size_t)row * (D >> 2) + i] = make_ushort4(h[0], h[1], h[2], h[3]);
    }
    __shared__ float s1[128], s2[128];
    s1[t] = q; s2[t] = r; __syncthreads();
    for (int off = 64; off > 0; off >>= 1) {
        if (t < off) { s1[t] += s1[t + off]; s2[t] += s2[t + off]; }
        __syncthreads();
    }
    if (t == 0) {
        if (isX) xsq[row] = s1[0];
        else { wsq[row] = s1[0]; rel_sum[row] = s2[0]; }
    }
}

// --- kernel B: 1-pass hh bf16 MFMA screen GEMM + candidate-list epilogue -----
__global__ __launch_bounds__(256, 2) void k_gemm_act(
    const ushort_t* __restrict__ Xh, const ushort_t* __restrict__ Wh,
    const float* __restrict__ xsq, const float* __restrict__ wsq,
    const float* __restrict__ rs,
    float* __restrict__ tmaxA, int* __restrict__ cntA,
    float* __restrict__ actsA, int* __restrict__ idxsA,
    int K, int D)
{
    // k-loop: A plane @0 (8KB), B plane @8192 (8KB).
    // epilogue: redM[128*33]f @0, tmaxrow[128] @16896, cntL[128] @17408,
    //           lsActs[1024] @17920, lsIdx[1024] @22016  -> 26112 B
    __shared__ char smem[26112];

    const int tid = threadIdx.x;
    const int wave = tid >> 6, lane = tid & 63;
    const int nk = K / BN;
    const int bx = blockIdx.x % nk, by = blockIdx.x / nk;
    const int b0 = by * BM, k0 = bx * BN;

    const int srow = wave * 32 + (lane >> 2);
    const int schunk = ((lane & 3) - (lane >> 3)) & 3;
    const int scol = schunk * 8;
    const size_t gx = (size_t)(b0 + srow) * D + scol;
    const size_t gw = (size_t)(k0 + srow) * D + scol;
    const size_t c1 = (size_t)16 * D;
    char* lb = smem + wave * 2048;

    const int wm = wave >> 1, wn = wave & 1;
    const int l15 = lane & 15, quad = lane >> 4;
    const int roff = (l15 * 4 + ((quad + (l15 >> 1)) & 3)) * 16;
    const int aoff = (wm * 4) * 1024 + roff;
    const int boff = (wn * 4) * 1024 + roff;

    f32x4 acc[4][4];
#pragma unroll
    for (int i = 0; i < 4; i++)
#pragma unroll
        for (int j = 0; j < 4; j++) acc[i][j] = (f32x4){0.f, 0.f, 0.f, 0.f};

    for (int kd = 0; kd < D; kd += 32) {
        gll16(Xh + gx + kd,      lb + 0);
        gll16(Xh + gx + c1 + kd, lb + 1024);
        gll16(Wh + gw + kd,      lb + 8192);
        gll16(Wh + gw + c1 + kd, lb + 8192 + 1024);
        __syncthreads();

        bf16x8 ah[4], bh[4];
#pragma unroll
        for (int t = 0; t < 4; t++) {
            ah[t] = *(const bf16x8*)(smem + 0    + aoff + t * 1024);
            bh[t] = *(const bf16x8*)(smem + 8192 + boff + t * 1024);
        }
#pragma unroll
        for (int j = 0; j < 4; j++)
#pragma unroll
            for (int i = 0; i < 4; i++)
                acc[i][j] = __builtin_amdgcn_mfma_f32_16x16x32_bf16(ah[i], bh[j], acc[i][j], 0, 0, 0);
        __syncthreads();
    }

    // epilogue
    float rsv[4], wqv[4];
#pragma unroll
    for (int tn = 0; tn < 4; tn++) {
        int c = k0 + wn * 64 + tn * 16 + l15;
        rsv[tn] = rs[c]; wqv[tn] = wsq[c];
    }
    const float invD = 1.f / (float)D;
    float* redM    = (float*)smem;              // [128][33]
    float* tmaxrow = (float*)(smem + 16896);    // [128]
    int*   cntL    = (int*)(smem + 17408);      // [128]
    float* lsActs  = (float*)(smem + 17920);    // [128][8]
    int*   lsIdx   = (int*)(smem + 22016);      // [128][8]

    // pass 1: per-thread max over its 4 cols -> redM
#pragma unroll
    for (int tm = 0; tm < 4; tm++) {
#pragma unroll
        for (int r = 0; r < 4; r++) {
            int rowl = wm * 64 + tm * 16 + quad * 4 + r;
            float xq = xsq[b0 + rowl];
            float m = -1e30f;
#pragma unroll
            for (int tn = 0; tn < 4; tn++) {
                float dd = (xq + wqv[tn]) - 2.f * acc[tm][tn][r];
                float dw = dd * (rsv[tn] * invD);
                if (dw != dw) dw = 0.f;
                float act = rsv[tn] / ((rsv[tn] + dw) + 1e-7f);
                m = fmaxf(m, act);
            }
            redM[rowl * 33 + wn * 16 + l15] = m;
        }
    }
    __syncthreads();
    if (tid < BM) {
        float m = -1e30f;
#pragma unroll
        for (int t2 = 0; t2 < 32; t2++) m = fmaxf(m, redM[tid * 33 + t2]);
        tmaxrow[tid] = m;
        cntL[tid] = 0;
    }
    __syncthreads();
    // pass 2: collect candidates within DELTA of tile max
#pragma unroll
    for (int tm = 0; tm < 4; tm++) {
#pragma unroll
        for (int r = 0; r < 4; r++) {
            int rowl = wm * 64 + tm * 16 + quad * 4 + r;
            float xq = xsq[b0 + rowl];
            float thr = tmaxrow[rowl] - DELTA;
#pragma unroll
            for (int tn = 0; tn < 4; tn++) {
                float dd = (xq + wqv[tn]) - 2.f * acc[tm][tn][r];
                float dw = dd * (rsv[tn] * invD);
                if (dw != dw) dw = 0.f;
                float act = rsv[tn] / ((rsv[tn] + dw) + 1e-7f);
                if (act >= thr) {
                    int pos = atomicAdd(&cntL[rowl], 1);
                    if (pos < 8) {
                        lsActs[rowl * 8 + pos] = act;
                        lsIdx[rowl * 8 + pos]  = k0 + wn * 64 + tn * 16 + l15;
                    }
                }
            }
        }
    }
    __syncthreads();
    if (tid < BM) {
        size_t base = (size_t)(b0 + tid) * nk + bx;
        tmaxA[base] = tmaxrow[tid];
        int c = cntL[tid];
        cntA[base] = c;
        int cc = c < 8 ? c : 8;
        for (int s = 0; s < cc; s++) {
            actsA[base * 8 + s] = lsActs[tid * 8 + s];
            idxsA[base * 8 + s] = lsIdx[tid * 8 + s];
        }
    }
}

// ---- kernel C: exact fp32 refine of candidates + BMU + rank -----------------
__global__ __launch_bounds__(64) void k_refine(
    const float* __restrict__ X, const float* __restrict__ W,
    const float* __restrict__ xsq, const float* __restrict__ wsq,
    const float* __restrict__ rs,
    const float* __restrict__ tmaxA, const int* __restrict__ cntA,
    const float* __restrict__ actsA, const int* __restrict__ idxsA,
    int nk, int* __restrict__ cnt, int* __restrict__ cnt_l,
    int* __restrict__ idxb, int* __restrict__ rankb, int* __restrict__ highb,
    int K, int D)
{
    int b = blockIdx.x, ln = threadIdx.x;
    // cache x row: 8 floats per lane
    const float4* xp = (const float4*)(X + (size_t)b * D + ln * 8);
    float4 xa = xp[0], xb = xp[1];
    float xr[8] = {xa.x, xa.y, xa.z, xa.w, xb.x, xb.y, xb.z, xb.w};
    float xq = xsq[b];
    const float invD = 1.f / (float)D;

    float tmax = (ln < nk) ? tmaxA[(size_t)b * nk + ln] : -1e30f;
    int   tcnt = (ln < nk) ? cntA[(size_t)b * nk + ln] : 0;
    float M = tmax;
#pragma unroll
    for (int o = 32; o > 0; o >>= 1) M = fmaxf(M, __shfl_xor(M, o));
    float thr = M - DELTA;

    float best = -1e30f; int bidx = 0x7fffffff;

    auto exact_upd = [&](int idx) {
        const float* wr = W + (size_t)idx * D + ln * 8;
        float p = 0.f;
#pragma unroll
        for (int j = 0; j < 8; j++) p = fmaf(xr[j], wr[j], p);
#pragma unroll
        for (int o = 32; o > 0; o >>= 1) p += __shfl_xor(p, o);
        float rsv = rs[idx];
        float dd = (xq + wsq[idx]) - 2.f * p;
        float dw = dd * (rsv * invD);
        if (dw != dw) dw = 0.f;
        float act = rsv / ((rsv + dw) + 1e-7f);
        if (act > best || (act == best && idx < bidx)) { best = act; bidx = idx; }
    };

    for (int t = 0; t < nk; t++) {
        float tm = __shfl(tmax, t);
        int   tc = __shfl(tcnt, t);
        if (tm < thr) continue;
        if (tc <= 8) {
            size_t base = ((size_t)b * nk + t) * 8;
            for (int s = 0; s < tc; s++) {
                float aact = actsA[base + s];
                if (aact < thr) continue;
                exact_upd(idxsA[base + s]);
            }
        } else {
            // overflow (ultra-rare): exact-scan the whole 128-col tile
            for (int k2 = t * BN; k2 < t * BN + BN; k2++) exact_upd(k2);
        }
    }

    if (ln == 0) {
        int hi = (best >= ATC) ? 1 : 0;
        int rank = atomicAdd((hi ? cnt : cnt_l) + bidx, 1);
        idxb[b] = bidx; rankb[b] = rank; highb[b] = hi;
    }
}

// ---- kernel D: offsets (prefix sums) + low/avail compaction (one block) -----
__global__ __launch_bounds__(1024) void k_offsets(
    const int* __restrict__ cnt, const int* __restrict__ cnt_l,
    const float* __restrict__ NC,
    int* __restrict__ offs_h, int* __restrict__ offs_l,
    int* __restrict__ low_ids, int* __restrict__ avail_ids,
    int* __restrict__ scal, int K)
{
    __shared__ int sA[1024], sB[1024];
    int t = threadIdx.x;
    int per = (K + 1023) / 1024;     // 4
    int base = t * per;
    int ch[8], cl[8]; int sh = 0, sl = 0;
    for (int j = 0; j < per; j++) {
        int k = base + j;
        int a = (k < K) ? cnt[k] : 0;
        int b = (k < K) ? cnt_l[k] : 0;
        ch[j] = a; cl[j] = b; sh += a; sl += b;
    }
    sA[t] = sh; sB[t] = sl; __syncthreads();
    for (int off = 1; off < 1024; off <<= 1) {
        int vA = (t >= off) ? sA[t - off] : 0;
        int vB = (t >= off) ? sB[t - off] : 0;
        __syncthreads();
        sA[t] += vA; sB[t] += vB;
        __syncthreads();
    }
    int eh = sA[t] - sh, el = sB[t] - sl;
    for (int j = 0; j < per; j++) {
        int k = base + j;
        if (k < K) { offs_h[k] = eh; offs_l[k] = el; }
        eh += ch[j]; el += cl[j];
    }
    __syncthreads();
    int lv[8], av[8]; int cL = 0, cA = 0;
    for (int j = 0; j < per; j++) {
        int k = base + j;
        int l = 0, a = 0;
        if (k < K) {
            l = (cl[j] > 0) ? 1 : 0;
            float nc1 = (ch[j] > 0) ? 1.f : NC[k];
            a = (nc1 == 0.f) ? 1 : 0;
        }
        lv[j] = l; av[j] = a; cL += l; cA += a;
    }
    sA[t] = cL; sB[t] = cA; __syncthreads();
    for (int off = 1; off < 1024; off <<= 1) {
        int vA = (t >= off) ? sA[t - off] : 0;
        int vB = (t >= off) ? sB[t - off] : 0;
        __syncthreads();
        sA[t] += vA; sB[t] += vB;
        __syncthreads();
    }
    int totL = sA[1023], totA = sB[1023];
    int eL = sA[t] - cL, eA = sB[t] - cA;
    for (int j = 0; j < per; j++) {
        if (lv[j]) low_ids[eL++] = base + j;
        if (av[j]) avail_ids[eA++] = base + j;
    }
    if (t == 0) {
        scal[0] = totL;
        scal[1] = totA;
        scal[2] = (totL < totA) ? totL : totA;
    }
}

// ---- kernel E: scatter sample ids into per-node lists -----------------------
__global__ __launch_bounds__(256) void k_scatter(
    const int* __restrict__ idxb, const int* __restrict__ rankb,
    const int* __restrict__ highb,
    const int* __restrict__ offs_h, const int* __restrict__ offs_l,
    int* __restrict__ list_h, int* __restrict__ list_l, int B)
{
    int b = blockIdx.x * 256 + threadIdx.x;
    if (b >= B) return;
    int node = idxb[b];
    if (highb[b]) list_h[offs_h[node] + rankb[b]] = b;
    else          list_l[offs_l[node] + rankb[b]] = b;
}

// ---- kernel F: per-node high-branch update (list gather, D == 512) ----------
__global__ __launch_bounds__(256) void k_high_update(
    const float* __restrict__ X,
    const float* __restrict__ W, const float* __restrict__ MA,
    const float* __restrict__ REL, const float* __restrict__ NC,
    const int* __restrict__ cnt, const int* __restrict__ offs_h,
    const int* __restrict__ list_h,
    float* __restrict__ outW, float* __restrict__ outMA,
    float* __restrict__ outREL, float* __restrict__ outNC,
    float* __restrict__ outLoss, int D, float invB)
{
    int k = blockIdx.x, t = threadIdx.x;
    size_t ro = (size_t)k * D;
    int n = cnt[k];
    int t2 = t + 256;
    __shared__ float rbuf[12];
    if (n > 0) {
        float s0 = 0.f, s1 = 0.f;
        int base = offs_h[k];
        for (int i = 0; i < n; i++) {
            int b = list_h[base + i];
            const float* xr = X + (size_t)b * D;
            s0 += xr[t]; s1 += xr[t2];
        }
        float fn = (float)n;
        float mean0 = s0 / fn, mean1 = s1 / fn;
        float w0 = W[ro + t],  w1 = W[ro + t2];
        float a0 = MA[ro + t], a1 = MA[ro + t2];
        float m0 = AC * fabsf(mean0 - w0) + OMAC * a0;
        float m1 = AC * fabsf(mean1 - w1) + OMAC * a1;

        float vmax = fmaxf(m0, m1), vmin = fminf(m0, m1), vsum = m0 + m1;
#pragma unroll
        for (int o = 1; o < 64; o <<= 1) {
            vmax = fmaxf(vmax, __shfl_xor(vmax, o));
            vmin = fminf(vmin, __shfl_xor(vmin, o));
            vsum += __shfl_xor(vsum, o);
        }
        int wv = t >> 6, ln = t & 63;
        if (ln == 0) { rbuf[wv] = vmax; rbuf[4 + wv] = vmin; rbuf[8 + wv] = vsum; }
        __syncthreads();
        float mx = fmaxf(fmaxf(rbuf[0], rbuf[1]), fmaxf(rbuf[2], rbuf[3]));
        float mn = fminf(fminf(rbuf[4], rbuf[5]), fminf(rbuf[6], rbuf[7]));
        float av = (rbuf[8] + rbuf[9] + rbuf[10] + rbuf[11]) / (float)D;

        float scale = EPSC * (mx - mn);
        float r0 = 1.f / (1.f + expf((m0 - av) / scale));
        float r1 = 1.f / (1.f + expf((m1 - av) / scale));
        float d0 = LRC * (mean0 - w0), d1 = LRC * (mean1 - w1);

        outW[ro + t]  = w0 + d0;  outW[ro + t2]  = w1 + d1;
        outMA[ro + t] = m0;       outMA[ro + t2] = m1;
        outREL[ro + t] = r0;      outREL[ro + t2] = r1;

        float ls = d0 + d1;
#pragma unroll
        for (int o = 1; o < 64; o <<= 1) ls += __shfl_xor(ls, o);
        __syncthreads();
        if (ln == 0) rbuf[wv] = ls;
        __syncthreads();
        if (t == 0) {
            atomicAdd(outLoss, (rbuf[0] + rbuf[1] + rbuf[2] + rbuf[3]) * invB);
            outNC[k] = 1.f;
        }
    } else {
        outW[ro + t]  = W[ro + t];   outW[ro + t2]  = W[ro + t2];
        outMA[ro + t] = MA[ro + t];  outMA[ro + t2] = MA[ro + t2];
        outREL[ro + t] = REL[ro + t]; outREL[ro + t2] = REL[ro + t2];
        if (t == 0) outNC[k] = NC[k];
    }
}

// ---- kernel G: add-node scatter (list gather means) -------------------------
__global__ __launch_bounds__(256) void k_addnode(
    const float* __restrict__ X,
    const int* __restrict__ cnt_l, const int* __restrict__ offs_l,
    const int* __restrict__ list_l,
    const int* __restrict__ low_ids, const int* __restrict__ avail_ids,
    const int* __restrict__ scal,
    float* __restrict__ outW, float* __restrict__ outMA,
    float* __restrict__ outREL, float* __restrict__ outNC, int D)
{
    int r = blockIdx.x;
    int n_create = scal[2], n_new = scal[0];
    if (r >= n_create) return;
    int slot = avail_ids[r];
    int src  = low_ids[n_new - n_create + r];
    int n = cnt_l[src];
    int t = threadIdx.x, t2 = t + 256;
    float s0 = 0.f, s1 = 0.f;
    int base = offs_l[src];
    for (int i = 0; i < n; i++) {
        int b = list_l[base + i];
        const float* xr = X + (size_t)b * D;
        s0 += xr[t]; s1 += xr[t2];
    }
    float fn = (float)n;
    size_t to = (size_t)slot * D;
    outW[to + t]  = s0 / fn;  outW[to + t2]  = s1 / fn;
    outMA[to + t] = 0.f;      outMA[to + t2] = 0.f;
    outREL[to + t] = 1.f;     outREL[to + t2] = 1.f;
    if (t == 0) outNC[slot] = 1.f;
}

// ---------------- launch -----------------------------------------------------
extern "C" void kernel_launch(void* const* d_in, const int* in_sizes, int n_in,
                              void* d_out, int out_size, void* d_ws, size_t ws_size,
                              hipStream_t stream) {
    const float* X   = (const float*)d_in[0];
    const float* W   = (const float*)d_in[1];
    const float* MA  = (const float*)d_in[2];
    const float* REL = (const float*)d_in[3];
    const float* NC  = (const float*)d_in[4];

    const int K = in_sizes[4];              // 4096
    const int D = in_sizes[1] / K;          // 512
    const int B = in_sizes[0] / D;          // 8192
    const int NKT = K / BN;                 // 32
    const size_t KD = (size_t)K * D;
    const size_t BD = (size_t)B * D;

    float* out = (float*)d_out;
    float* outLoss = out;
    float* outW   = out + 1;
    float* outMA  = out + 1 + KD;
    float* outREL = out + 1 + 2 * KD;
    float* outNC  = out + 1 + 3 * KD;

    float* wsf = (float*)d_ws;
    size_t off = 0;
    ushort_t* Xh = (ushort_t*)(wsf + off); off += BD / 2;
    ushort_t* Wh = (ushort_t*)(wsf + off); off += KD / 2;
    float* rel_sum = wsf + off; off += K;
    float* wsq     = wsf + off; off += K;
    float* xsq     = wsf + off; off += B;
    float* tmaxA   = wsf + off; off += (size_t)B * NKT;
    int*   cntA    = (int*)(wsf + off); off += (size_t)B * NKT;
    float* actsA   = wsf + off; off += (size_t)B * NKT * 8;
    int*   idxsA   = (int*)(wsf + off); off += (size_t)B * NKT * 8;
    int*   idxb    = (int*)(wsf + off); off += B;
    int*   rankb   = (int*)(wsf + off); off += B;
    int*   highb   = (int*)(wsf + off); off += B;
    int*   list_h  = (int*)(wsf + off); off += B;
    int*   list_l  = (int*)(wsf + off); off += B;
    int*   offs_h  = (int*)(wsf + off); off += K;
    int*   offs_l  = (int*)(wsf + off); off += K;
    int*   low_ids   = (int*)(wsf + off); off += K;
    int*   avail_ids = (int*)(wsf + off); off += K;
    int*   scal    = (int*)(wsf + off); off += 16;
    int*   cnt     = (int*)(wsf + off); off += K;
    int*   cnt_l   = (int*)(wsf + off); off += K;

    hipMemsetAsync(cnt, 0, 2 * (size_t)K * sizeof(int), stream);
    hipMemsetAsync(outLoss, 0, sizeof(float), stream);

    k_prep<<<B + K, 128, 0, stream>>>(X, W, REL, Xh, Wh, xsq, wsq, rel_sum, B, D);
    k_gemm_act<<<(B / BM) * (K / BN), 256, 0, stream>>>(Xh, Wh, xsq, wsq, rel_sum,
                                                        tmaxA, cntA, actsA, idxsA,
                                                        K, D);
    k_refine<<<B, 64, 0, stream>>>(X, W, xsq, wsq, rel_sum,
                                   tmaxA, cntA, actsA, idxsA, NKT,
                                   cnt, cnt_l, idxb, rankb, highb, K, D);
    k_offsets<<<1, 1024, 0, stream>>>(cnt, cnt_l, NC, offs_h, offs_l,
                                      low_ids, avail_ids, scal, K);
    k_scatter<<<(B + 255) / 256, 256, 0, stream>>>(idxb, rankb, highb,
                                                   offs_h, offs_l,
                                                   list_h, list_l, B);
    k_high_update<<<K, 256, 0, stream>>>(X, W, MA, REL, NC, cnt, offs_h, list_h,
                                         outW, outMA, outREL, outNC, outLoss,
                                         D, 1.f / (float)B);
    k_addnode<<<K, 256, 0, stream>>>(X, cnt_l, offs_l, list_l,
                                     low_ids, avail_ids, scal,
                                     outW, outMA, outREL, outNC, D);
}

// Round 8
// 251.639 us; speedup vs baseline: 1.7592x; 1.0565x over previous
//
#include <hip/hip_runtime.h>

typedef unsigned short ushort_t;
typedef unsigned int uint_t;
typedef __bf16 bf16x8 __attribute__((ext_vector_type(8)));
typedef float f32x4 __attribute__((ext_vector_type(4)));

#define BM 128
#define BN 128

static constexpr float LRC  = 0.3f;
static constexpr float AC   = (float)(0.3 * 1e-4);          // LR*DSBETA
static constexpr float OMAC = (float)(1.0 - 0.3 * 1e-4);    // 1 - LR*DSBETA
static constexpr float EPSC = 0.01f;                        // EPS_DS
static constexpr float ATC  = 0.9f;                         // AT
static constexpr float DELTA = 5e-4f;   // screen margin, ~33 sigma of hh act err

__device__ __forceinline__ void gll16(const void* g, void* l) {
    __builtin_amdgcn_global_load_lds((__attribute__((address_space(1))) void*)g,
                                     (__attribute__((address_space(3))) void*)l,
                                     16, 0, 0);
}

__device__ __forceinline__ ushort_t f2bf_rne(float f) {
    uint_t u = __float_as_uint(f);
    uint_t r = u + 0x7fffu + ((u >> 16) & 1u);
    return (ushort_t)(r >> 16);
}

// -------- kernel A: prep: X/W -> hi bf16 plane + row stats -------------------
__global__ __launch_bounds__(128) void k_prep(
    const float* __restrict__ X, const float* __restrict__ W,
    const float* __restrict__ REL,
    ushort_t* __restrict__ Xh, ushort_t* __restrict__ Wh,
    float* __restrict__ xsq, float* __restrict__ wsq, float* __restrict__ rel_sum,
    int B, int D)
{
    int blk = blockIdx.x, t = threadIdx.x;
    bool isX = blk < B;
    int row = isX ? blk : blk - B;
    const float4* src = (const float4*)((isX ? X : W) + (size_t)row * D);
    const float4* rr  = isX ? nullptr : (const float4*)(REL + (size_t)row * D);
    ushort_t* H = isX ? Xh : Wh;
    float q = 0.f, r = 0.f;
    for (int i = t; i < (D >> 2); i += 128) {
        float4 v = src[i];
        if (!isX) { float4 rv = rr[i]; r += rv.x + rv.y + rv.z + rv.w; }
        float x[4] = {v.x, v.y, v.z, v.w};
        ushort_t h[4];
#pragma unroll
        for (int j = 0; j < 4; j++) { q += x[j] * x[j]; h[j] = f2bf_rne(x[j]); }
        ((ushort4*)H)[(size_t)row * (D >> 2) + i] = make_ushort4(h[0], h[1], h[2], h[3]);
    }
    __shared__ float s1[128], s2[128];
    s1[t] = q; s2[t] = r; __syncthreads();
    for (int off = 64; off > 0; off >>= 1) {
        if (t < off) { s1[t] += s1[t + off]; s2[t] += s2[t + off]; }
        __syncthreads();
    }
    if (t == 0) {
        if (isX) xsq[row] = s1[0];
        else { wsq[row] = s1[0]; rel_sum[row] = s2[0]; }
    }
}

// --- kernel B: 1-pass hh bf16 MFMA screen GEMM, division-free q-space epilogue
// act = rs/(rs+dw+1e-7) = 1/(1+q), q = dd/D + 1e-7/rs  (monotone: max act == min q)
__global__ __launch_bounds__(256, 2) void k_gemm_act(
    const ushort_t* __restrict__ Xh, const ushort_t* __restrict__ Wh,
    const float* __restrict__ xsq, const float* __restrict__ wsq,
    const float* __restrict__ rs,
    float* __restrict__ tmaxA, int* __restrict__ cntA,
    float* __restrict__ actsA, int* __restrict__ idxsA,
    int K, int D)
{
    // k-loop: A plane @0 (8KB), B plane @8192 (8KB).
    // epilogue: redM(q) [128][33] @0, tmaxrow @16896, thrq @17408, cntL @17920,
    //           lsActs @18432 (4KB), lsIdx @22528 (4KB) -> 26624 B
    __shared__ char smem[26624];

    const int tid = threadIdx.x;
    const int wave = tid >> 6, lane = tid & 63;
    const int nk = K / BN;
    const int bx = blockIdx.x % nk, by = blockIdx.x / nk;
    const int b0 = by * BM, k0 = bx * BN;

    const int srow = wave * 32 + (lane >> 2);
    const int schunk = ((lane & 3) - (lane >> 3)) & 3;
    const int scol = schunk * 8;
    const size_t gx = (size_t)(b0 + srow) * D + scol;
    const size_t gw = (size_t)(k0 + srow) * D + scol;
    const size_t c1 = (size_t)16 * D;
    char* lb = smem + wave * 2048;

    const int wm = wave >> 1, wn = wave & 1;
    const int l15 = lane & 15, quad = lane >> 4;
    const int roff = (l15 * 4 + ((quad + (l15 >> 1)) & 3)) * 16;
    const int aoff = (wm * 4) * 1024 + roff;
    const int boff = (wn * 4) * 1024 + roff;

    f32x4 acc[4][4];
#pragma unroll
    for (int i = 0; i < 4; i++)
#pragma unroll
        for (int j = 0; j < 4; j++) acc[i][j] = (f32x4){0.f, 0.f, 0.f, 0.f};

    for (int kd = 0; kd < D; kd += 32) {
        gll16(Xh + gx + kd,      lb + 0);
        gll16(Xh + gx + c1 + kd, lb + 1024);
        gll16(Wh + gw + kd,      lb + 8192);
        gll16(Wh + gw + c1 + kd, lb + 8192 + 1024);
        __syncthreads();

        bf16x8 ah[4], bh[4];
#pragma unroll
        for (int t = 0; t < 4; t++) {
            ah[t] = *(const bf16x8*)(smem + 0    + aoff + t * 1024);
            bh[t] = *(const bf16x8*)(smem + 8192 + boff + t * 1024);
        }
#pragma unroll
        for (int j = 0; j < 4; j++)
#pragma unroll
            for (int i = 0; i < 4; i++)
                acc[i][j] = __builtin_amdgcn_mfma_f32_16x16x32_bf16(ah[i], bh[j], acc[i][j], 0, 0, 0);
        __syncthreads();
    }

    // ---------------- epilogue (q-space, division-free hot path) -------------
    float rsv[4], wqv[4], epsors[4];
#pragma unroll
    for (int tn = 0; tn < 4; tn++) {
        int c = k0 + wn * 64 + tn * 16 + l15;
        float rv = rs[c];
        rsv[tn] = rv; wqv[tn] = wsq[c];
        epsors[tn] = 1e-7f / rv;
    }
    const float invD = 1.f / (float)D;
    float* redM    = (float*)smem;              // [128][33]  qmin
    float* tmaxrow = (float*)(smem + 16896);    // [128] act units
    float* thrqrow = (float*)(smem + 17408);    // [128] q units
    int*   cntL    = (int*)(smem + 17920);      // [128]
    float* lsActs  = (float*)(smem + 18432);    // [128][8]
    int*   lsIdx   = (int*)(smem + 22528);      // [128][8]

    // pass 1: q in place, per-thread row-min -> redM
#pragma unroll
    for (int tm = 0; tm < 4; tm++) {
#pragma unroll
        for (int r = 0; r < 4; r++) {
            int rowl = wm * 64 + tm * 16 + quad * 4 + r;
            float xq = xsq[b0 + rowl];
            float qmin = 1e30f;
#pragma unroll
            for (int tn = 0; tn < 4; tn++) {
                float dd = (xq + wqv[tn]) - 2.f * acc[tm][tn][r];
                float q = dd * invD + epsors[tn];
                acc[tm][tn][r] = q;
                qmin = fminf(qmin, q);
            }
            redM[rowl * 33 + wn * 16 + l15] = qmin;
        }
    }
    __syncthreads();
    if (tid < BM) {
        float qm = 1e30f;
#pragma unroll
        for (int t2 = 0; t2 < 32; t2++) qm = fminf(qm, redM[tid * 33 + t2]);
        float tmax = 1.f / (1.f + qm);
        tmaxrow[tid] = tmax;
        thrqrow[tid] = 1.f / (tmax - DELTA) - 1.f;
        cntL[tid] = 0;
    }
    __syncthreads();
    // pass 2: candidates q <= thrq (act >= tilemax - DELTA)
#pragma unroll
    for (int tm = 0; tm < 4; tm++) {
#pragma unroll
        for (int r = 0; r < 4; r++) {
            int rowl = wm * 64 + tm * 16 + quad * 4 + r;
            float tq = thrqrow[rowl];
#pragma unroll
            for (int tn = 0; tn < 4; tn++) {
                float q = acc[tm][tn][r];
                if (q <= tq) {
                    int pos = atomicAdd(&cntL[rowl], 1);
                    if (pos < 8) {
                        lsActs[rowl * 8 + pos] = 1.f / (1.f + q);
                        lsIdx[rowl * 8 + pos]  = k0 + wn * 64 + tn * 16 + l15;
                    }
                }
            }
        }
    }
    __syncthreads();
    if (tid < BM) {
        size_t base = (size_t)(b0 + tid) * nk + bx;
        tmaxA[base] = tmaxrow[tid];
        int c = cntL[tid];
        cntA[base] = c;
        int cc = c < 8 ? c : 8;
        for (int s = 0; s < cc; s++) {
            actsA[base * 8 + s] = lsActs[tid * 8 + s];
            idxsA[base * 8 + s] = lsIdx[tid * 8 + s];
        }
    }
}

// ---- kernel C: exact fp32 refine of candidates + BMU + rank -----------------
__global__ __launch_bounds__(64) void k_refine(
    const float* __restrict__ X, const float* __restrict__ W,
    const float* __restrict__ xsq, const float* __restrict__ wsq,
    const float* __restrict__ rs,
    const float* __restrict__ tmaxA, const int* __restrict__ cntA,
    const float* __restrict__ actsA, const int* __restrict__ idxsA,
    int nk, int* __restrict__ cnt, int* __restrict__ cnt_l,
    int* __restrict__ idxb, int* __restrict__ rankb, int* __restrict__ highb,
    int K, int D)
{
    int b = blockIdx.x, ln = threadIdx.x;
    const float4* xp = (const float4*)(X + (size_t)b * D + ln * 8);
    float4 xa = xp[0], xb = xp[1];
    float xr[8] = {xa.x, xa.y, xa.z, xa.w, xb.x, xb.y, xb.z, xb.w};
    float xq = xsq[b];
    const float invD = 1.f / (float)D;

    float tmax = (ln < nk) ? tmaxA[(size_t)b * nk + ln] : -1e30f;
    int   tcnt = (ln < nk) ? cntA[(size_t)b * nk + ln] : 0;
    float M = tmax;
#pragma unroll
    for (int o = 32; o > 0; o >>= 1) M = fmaxf(M, __shfl_xor(M, o));
    float thr = M - DELTA;

    float best = -1e30f; int bidx = 0x7fffffff;

    auto exact_upd = [&](int idx) {
        const float* wr = W + (size_t)idx * D + ln * 8;
        float p = 0.f;
#pragma unroll
        for (int j = 0; j < 8; j++) p = fmaf(xr[j], wr[j], p);
#pragma unroll
        for (int o = 32; o > 0; o >>= 1) p += __shfl_xor(p, o);
        float rsv = rs[idx];
        float dd = (xq + wsq[idx]) - 2.f * p;
        float dw = dd * (rsv * invD);
        if (dw != dw) dw = 0.f;
        float act = rsv / ((rsv + dw) + 1e-7f);
        if (act > best || (act == best && idx < bidx)) { best = act; bidx = idx; }
    };

    for (int t = 0; t < nk; t++) {
        float tm = __shfl(tmax, t);
        int   tc = __shfl(tcnt, t);
        if (tm < thr) continue;
        if (tc <= 8) {
            size_t base = ((size_t)b * nk + t) * 8;
            for (int s = 0; s < tc; s++) {
                float aact = actsA[base + s];
                if (aact < thr) continue;
                exact_upd(idxsA[base + s]);
            }
        } else {
            for (int k2 = t * BN; k2 < t * BN + BN; k2++) exact_upd(k2);
        }
    }

    if (ln == 0) {
        int hi = (best >= ATC) ? 1 : 0;
        int rank = atomicAdd((hi ? cnt : cnt_l) + bidx, 1);
        idxb[b] = bidx; rankb[b] = rank; highb[b] = hi;
    }
}

// ---- kernel D: offsets + slot_src map (one block) ---------------------------
__global__ __launch_bounds__(1024) void k_offsets(
    const int* __restrict__ cnt, const int* __restrict__ cnt_l,
    const float* __restrict__ NC,
    int* __restrict__ offs_h, int* __restrict__ offs_l,
    int* __restrict__ slot_src, int K)
{
    __shared__ int sA[1024], sB[1024];
    __shared__ int lowL[4096], availL[4096];
    int t = threadIdx.x;
    int per = (K + 1023) / 1024;     // 4
    int base = t * per;
    // ---- pass 1: exclusive offsets for high and low lists ----
    int ch[8], cl[8]; int sh = 0, sl = 0;
    for (int j = 0; j < per; j++) {
        int k = base + j;
        int a = (k < K) ? cnt[k] : 0;
        int b = (k < K) ? cnt_l[k] : 0;
        ch[j] = a; cl[j] = b; sh += a; sl += b;
    }
    sA[t] = sh; sB[t] = sl; __syncthreads();
    for (int off = 1; off < 1024; off <<= 1) {
        int vA = (t >= off) ? sA[t - off] : 0;
        int vB = (t >= off) ? sB[t - off] : 0;
        __syncthreads();
        sA[t] += vA; sB[t] += vB;
        __syncthreads();
    }
    int eh = sA[t] - sh, el = sB[t] - sl;
    for (int j = 0; j < per; j++) {
        int k = base + j;
        if (k < K) { offs_h[k] = eh; offs_l[k] = el; }
        eh += ch[j]; el += cl[j];
    }
    __syncthreads();
    // ---- pass 2: low_valid / avail compaction (into LDS) ----
    int lv[8], av[8]; int cL = 0, cA = 0;
    for (int j = 0; j < per; j++) {
        int k = base + j;
        int l = 0, a = 0;
        if (k < K) {
            l = (cl[j] > 0) ? 1 : 0;
            float nc1 = (ch[j] > 0) ? 1.f : NC[k];
            a = (nc1 == 0.f) ? 1 : 0;
        }
        lv[j] = l; av[j] = a; cL += l; cA += a;
    }
    sA[t] = cL; sB[t] = cA; __syncthreads();
    for (int off = 1; off < 1024; off <<= 1) {
        int vA = (t >= off) ? sA[t - off] : 0;
        int vB = (t >= off) ? sB[t - off] : 0;
        __syncthreads();
        sA[t] += vA; sB[t] += vB;
        __syncthreads();
    }
    int totL = sA[1023], totA = sB[1023];
    int eL = sA[t] - cL, eA = sB[t] - cA;
    for (int j = 0; j < per; j++) {
        if (lv[j]) lowL[eL++] = base + j;
        if (av[j]) availL[eA++] = base + j;
    }
    // init slot_src = -1
    for (int j = 0; j < per; j++) {
        int k = base + j;
        if (k < K) slot_src[k] = -1;
    }
    __syncthreads();   // drains global writes (lists are in LDS; -1 in global)
    int n_create = (totL < totA) ? totL : totA;
    for (int r = t; r < n_create; r += 1024)
        slot_src[availL[r]] = lowL[totL - n_create + r];
}

// ---- kernel E: scatter sample ids into per-node lists -----------------------
__global__ __launch_bounds__(256) void k_scatter(
    const int* __restrict__ idxb, const int* __restrict__ rankb,
    const int* __restrict__ highb,
    const int* __restrict__ offs_h, const int* __restrict__ offs_l,
    int* __restrict__ list_h, int* __restrict__ list_l, int B)
{
    int b = blockIdx.x * 256 + threadIdx.x;
    if (b >= B) return;
    int node = idxb[b];
    if (highb[b]) list_h[offs_h[node] + rankb[b]] = b;
    else          list_l[offs_l[node] + rankb[b]] = b;
}

// ---- kernel F: fused per-node output (high update / created slot / copy) ----
__global__ __launch_bounds__(256) void k_final(
    const float* __restrict__ X,
    const float* __restrict__ W, const float* __restrict__ MA,
    const float* __restrict__ REL, const float* __restrict__ NC,
    const int* __restrict__ cnt, const int* __restrict__ offs_h,
    const int* __restrict__ list_h,
    const int* __restrict__ cnt_l, const int* __restrict__ offs_l,
    const int* __restrict__ list_l, const int* __restrict__ slot_src,
    float* __restrict__ outW, float* __restrict__ outMA,
    float* __restrict__ outREL, float* __restrict__ outNC,
    float* __restrict__ outLoss, int D, float invB)
{
    int k = blockIdx.x, t = threadIdx.x;
    size_t ro = (size_t)k * D;
    int t2 = t + 256;
    int src = slot_src[k];
    int n = cnt[k];
    __shared__ float rbuf[12];
    if (src >= 0) {
        // created slot: mean of low-list of src node (created slots have cnt==0)
        int m = cnt_l[src];
        int base = offs_l[src];
        float s0 = 0.f, s1 = 0.f;
        for (int i = 0; i < m; i++) {
            int b = list_l[base + i];
            const float* xr = X + (size_t)b * D;
            s0 += xr[t]; s1 += xr[t2];
        }
        float fm = (float)m;
        outW[ro + t]  = s0 / fm; outW[ro + t2]  = s1 / fm;
        outMA[ro + t] = 0.f;     outMA[ro + t2] = 0.f;
        outREL[ro + t] = 1.f;    outREL[ro + t2] = 1.f;
        if (t == 0) outNC[k] = 1.f;
    } else if (n > 0) {
        float s0 = 0.f, s1 = 0.f;
        int base = offs_h[k];
        for (int i = 0; i < n; i++) {
            int b = list_h[base + i];
            const float* xr = X + (size_t)b * D;
            s0 += xr[t]; s1 += xr[t2];
        }
        float fn = (float)n;
        float mean0 = s0 / fn, mean1 = s1 / fn;
        float w0 = W[ro + t],  w1 = W[ro + t2];
        float a0 = MA[ro + t], a1 = MA[ro + t2];
        float m0 = AC * fabsf(mean0 - w0) + OMAC * a0;
        float m1 = AC * fabsf(mean1 - w1) + OMAC * a1;

        float vmax = fmaxf(m0, m1), vmin = fminf(m0, m1), vsum = m0 + m1;
#pragma unroll
        for (int o = 1; o < 64; o <<= 1) {
            vmax = fmaxf(vmax, __shfl_xor(vmax, o));
            vmin = fminf(vmin, __shfl_xor(vmin, o));
            vsum += __shfl_xor(vsum, o);
        }
        int wv = t >> 6, ln = t & 63;
        if (ln == 0) { rbuf[wv] = vmax; rbuf[4 + wv] = vmin; rbuf[8 + wv] = vsum; }
        __syncthreads();
        float mx = fmaxf(fmaxf(rbuf[0], rbuf[1]), fmaxf(rbuf[2], rbuf[3]));
        float mn = fminf(fminf(rbuf[4], rbuf[5]), fminf(rbuf[6], rbuf[7]));
        float av = (rbuf[8] + rbuf[9] + rbuf[10] + rbuf[11]) / (float)D;

        float scale = EPSC * (mx - mn);
        float r0 = 1.f / (1.f + expf((m0 - av) / scale));
        float r1 = 1.f / (1.f + expf((m1 - av) / scale));
        float d0 = LRC * (mean0 - w0), d1 = LRC * (mean1 - w1);

        outW[ro + t]  = w0 + d0;  outW[ro + t2]  = w1 + d1;
        outMA[ro + t] = m0;       outMA[ro + t2] = m1;
        outREL[ro + t] = r0;      outREL[ro + t2] = r1;

        float ls = d0 + d1;
#pragma unroll
        for (int o = 1; o < 64; o <<= 1) ls += __shfl_xor(ls, o);
        __syncthreads();
        if (ln == 0) rbuf[wv] = ls;
        __syncthreads();
        if (t == 0) {
            atomicAdd(outLoss, (rbuf[0] + rbuf[1] + rbuf[2] + rbuf[3]) * invB);
            outNC[k] = 1.f;
        }
    } else {
        outW[ro + t]  = W[ro + t];   outW[ro + t2]  = W[ro + t2];
        outMA[ro + t] = MA[ro + t];  outMA[ro + t2] = MA[ro + t2];
        outREL[ro + t] = REL[ro + t]; outREL[ro + t2] = REL[ro + t2];
        if (t == 0) outNC[k] = NC[k];
    }
}

// ---------------- launch -----------------------------------------------------
extern "C" void kernel_launch(void* const* d_in, const int* in_sizes, int n_in,
                              void* d_out, int out_size, void* d_ws, size_t ws_size,
                              hipStream_t stream) {
    const float* X   = (const float*)d_in[0];
    const float* W   = (const float*)d_in[1];
    const float* MA  = (const float*)d_in[2];
    const float* REL = (const float*)d_in[3];
    const float* NC  = (const float*)d_in[4];

    const int K = in_sizes[4];              // 4096
    const int D = in_sizes[1] / K;          // 512
    const int B = in_sizes[0] / D;          // 8192
    const int NKT = K / BN;                 // 32
    const size_t KD = (size_t)K * D;
    const size_t BD = (size_t)B * D;

    float* out = (float*)d_out;
    float* outLoss = out;
    float* outW   = out + 1;
    float* outMA  = out + 1 + KD;
    float* outREL = out + 1 + 2 * KD;
    float* outNC  = out + 1 + 3 * KD;

    float* wsf = (float*)d_ws;
    size_t off = 0;
    ushort_t* Xh = (ushort_t*)(wsf + off); off += BD / 2;
    ushort_t* Wh = (ushort_t*)(wsf + off); off += KD / 2;
    float* rel_sum = wsf + off; off += K;
    float* wsq     = wsf + off; off += K;
    float* xsq     = wsf + off; off += B;
    float* tmaxA   = wsf + off; off += (size_t)B * NKT;
    int*   cntA    = (int*)(wsf + off); off += (size_t)B * NKT;
    float* actsA   = wsf + off; off += (size_t)B * NKT * 8;
    int*   idxsA   = (int*)(wsf + off); off += (size_t)B * NKT * 8;
    int*   idxb    = (int*)(wsf + off); off += B;
    int*   rankb   = (int*)(wsf + off); off += B;
    int*   highb   = (int*)(wsf + off); off += B;
    int*   list_h  = (int*)(wsf + off); off += B;
    int*   list_l  = (int*)(wsf + off); off += B;
    int*   offs_h  = (int*)(wsf + off); off += K;
    int*   offs_l  = (int*)(wsf + off); off += K;
    int*   slot_src = (int*)(wsf + off); off += K;
    int*   cnt     = (int*)(wsf + off); off += K;
    int*   cnt_l   = (int*)(wsf + off); off += K;

    hipMemsetAsync(cnt, 0, 2 * (size_t)K * sizeof(int), stream);
    hipMemsetAsync(outLoss, 0, sizeof(float), stream);

    k_prep<<<B + K, 128, 0, stream>>>(X, W, REL, Xh, Wh, xsq, wsq, rel_sum, B, D);
    k_gemm_act<<<(B / BM) * (K / BN), 256, 0, stream>>>(Xh, Wh, xsq, wsq, rel_sum,
                                                        tmaxA, cntA, actsA, idxsA,
                                                        K, D);
    k_refine<<<B, 64, 0, stream>>>(X, W, xsq, wsq, rel_sum,
                                   tmaxA, cntA, actsA, idxsA, NKT,
                                   cnt, cnt_l, idxb, rankb, highb, K, D);
    k_offsets<<<1, 1024, 0, stream>>>(cnt, cnt_l, NC, offs_h, offs_l,
                                      slot_src, K);
    k_scatter<<<(B + 255) / 256, 256, 0, stream>>>(idxb, rankb, highb,
                                                   offs_h, offs_l,
                                                   list_h, list_l, B);
    k_final<<<K, 256, 0, stream>>>(X, W, MA, REL, NC, cnt, offs_h, list_h,
                                   cnt_l, offs_l, list_l, slot_src,
                                   outW, outMA, outREL, outNC, outLoss,
                                   D, 1.f / (float)B);
}